// Round 12
// baseline (275.346 us; speedup 1.0000x reference)
//
#include <hip/hip_runtime.h>
#include <cstdint>

// ---- JAX PRNG mode switches -------------------------------------------------
#define JPART 1
#define PART_XOR 1

constexpr uint32_t N20   = 1u << 20;
constexpr uint32_t NHALF = 1u << 19;
constexpr int SPT_STRIDE = 520;   // padded row stride (float4 elems) for spT

struct Hdr {
  float e_r, e_i, amp_r, amp_i;
  int   phi_r, phi_i;
  float nhe_r, nhe_i;
  float scale_s[4];
};
struct KeyArgs { uint32_t k[8][2]; };

typedef __attribute__((ext_vector_type(8))) short short8;
typedef __attribute__((ext_vector_type(16))) float f32x16;

__device__ inline f32x16 zero16() {
  f32x16 v;
  #pragma unroll
  for (int i = 0; i < 16; ++i) v[i] = 0.f;
  return v;
}

__device__ inline unsigned short f2bf(float f) {
  uint32_t u = __float_as_uint(f);
  return (unsigned short)((u + 0x7fffu + ((u >> 16) & 1u)) >> 16);
}

// ---- Threefry2x32-20 (exact JAX cipher) ------------------------------------
__host__ __device__ inline void tf2x32(uint32_t k0, uint32_t k1, uint32_t x0, uint32_t x1,
                                       uint32_t& o0, uint32_t& o1) {
  const uint32_t ks0 = k0, ks1 = k1, ks2 = k0 ^ k1 ^ 0x1BD11BDAu;
  const uint32_t ks[3] = { ks0, ks1, ks2 };
  x0 += ks0; x1 += ks1;
  const int rot[2][4] = { {13,15,26,6}, {17,29,16,24} };
  for (int g = 0; g < 5; ++g) {
    const int* rr = rot[g & 1];
    for (int i = 0; i < 4; ++i) {
      x0 += x1;
      x1 = (x1 << rr[i]) | (x1 >> (32 - rr[i]));
      x1 ^= x0;
    }
    x0 += ks[(g + 1) % 3];
    x1 += ks[(g + 2) % 3] + (uint32_t)(g + 1);
  }
  o0 = x0; o1 = x1;
}

// ---- XLA ErfInv32 polynomial ------------------------------------------------
__device__ inline float erfinv_xla(float x) {
  float w = -log1pf(-x * x);
  float p;
  if (w < 5.0f) {
    w -= 2.5f;
    p = 2.81022636e-08f;
    p = fmaf(p, w, 3.43273939e-07f);
    p = fmaf(p, w, -3.5233877e-06f);
    p = fmaf(p, w, -4.39150654e-06f);
    p = fmaf(p, w, 0.00021858087f);
    p = fmaf(p, w, -0.00125372503f);
    p = fmaf(p, w, -0.00417768164f);
    p = fmaf(p, w, 0.246640727f);
    p = fmaf(p, w, 1.50140941f);
  } else {
    w = sqrtf(w) - 3.0f;
    p = -0.000200214257f;
    p = fmaf(p, w, 0.000100950558f);
    p = fmaf(p, w, 0.00134934322f);
    p = fmaf(p, w, -0.00367342844f);
    p = fmaf(p, w, 0.00573950773f);
    p = fmaf(p, w, -0.0076224613f);
    p = fmaf(p, w, 0.00943887047f);
    p = fmaf(p, w, 1.00167406f);
    p = fmaf(p, w, 2.83297682f);
  }
  return p * x;
}

__device__ inline float normal_from_bits(uint32_t bits) {
  uint32_t fb = (bits >> 9) | 0x3f800000u;
  float f = __uint_as_float(fb) - 1.0f;
  const float LO = -0.99999994f;
  float u = f * 2.0f + LO;
  u = fmaxf(LO, u);
  return 1.41421356f * erfinv_xla(u);
}

__device__ inline float sscale_f(uint32_t k, float nhe) {
  uint32_t kk = k ? k : 1u;
  return powf((float)kk * (1.0f / 1048576.0f), nhe);
}

__device__ inline float2 cmul(float2 a, float2 b) {
  return make_float2(a.x * b.x - a.y * b.y, a.x * b.y + a.y * b.x);
}
__device__ inline float2 wexp(float u) {
  float s, c; sincospif(2.0f * u, &s, &c); return make_float2(c, s);
}
__device__ inline float2 cadd(float2 a, float2 b){ return make_float2(a.x+b.x, a.y+b.y); }
__device__ inline float2 csub(float2 a, float2 b){ return make_float2(a.x-b.x, a.y-b.y); }
__device__ inline float2 cmuli(float2 a){ return make_float2(-a.y, a.x); }  // * (+i)

// LDS address swizzle for the FFT exchanges: <=4-way on all phases
__device__ inline int sA(int p) { return p ^ (((p >> 6) & 3) << 2) ^ ((p >> 8) & 3); }

// radix-4 DIF butterfly, sign +i, with twiddle W = omega^{n'}
__device__ inline void bfly(float2& y0, float2& y1, float2& y2, float2& y3, float2 W) {
  float2 a = cadd(y0, y2), b = csub(y0, y2);
  float2 c = cadd(y1, y3), d = cmuli(csub(y1, y3));
  float2 W2 = cmul(W, W), W3 = cmul(W2, W);
  y0 = cadd(a, c);
  y1 = cmul(cadd(b, d), W);
  y2 = cmul(csub(a, c), W2);
  y3 = cmul(csub(b, d), W3);
}

// 1024-pt FFT core (sign +), 64 threads, 16 pts/thread, 2 barriers.
__device__ inline void fft1024_core(float2* r, float2* rc, float2* buf, int w) {
  #pragma unroll
  for (int e3 = 0; e3 < 4; ++e3) {
    float2 W = wexp((float)((e3 << 6) + w) * (1.0f / 1024.0f));
    bfly(r[e3], r[e3 + 4], r[e3 + 8], r[e3 + 12], W);
  }
  {
    float2 W = wexp((float)w * (1.0f / 256.0f));
    #pragma unroll
    for (int e4 = 0; e4 < 4; ++e4)
      bfly(r[(e4 << 2) + 0], r[(e4 << 2) + 1], r[(e4 << 2) + 2], r[(e4 << 2) + 3], W);
  }
  #pragma unroll
  for (int s = 0; s < 16; ++s) buf[sA((s << 6) + w)] = r[s];
  __syncthreads();
  {
    const int e0 = w & 3;
    const int pbase = ((w >> 4) << 8) + (((w >> 2) & 3) << 6) + e0;
    float2 rb[16];
    #pragma unroll
    for (int e2 = 0; e2 < 4; ++e2)
      #pragma unroll
      for (int e1 = 0; e1 < 4; ++e1)
        rb[(e2 << 2) + e1] = buf[sA(pbase + (e2 << 4) + (e1 << 2))];
    #pragma unroll
    for (int e1 = 0; e1 < 4; ++e1) {
      float2 W = wexp((float)((e1 << 2) + e0) * (1.0f / 64.0f));
      bfly(rb[e1], rb[e1 + 4], rb[e1 + 8], rb[e1 + 12], W);
    }
    {
      float2 W = wexp((float)e0 * (1.0f / 16.0f));
      #pragma unroll
      for (int e2 = 0; e2 < 4; ++e2)
        bfly(rb[(e2 << 2) + 0], rb[(e2 << 2) + 1], rb[(e2 << 2) + 2], rb[(e2 << 2) + 3], W);
    }
    #pragma unroll
    for (int e2 = 0; e2 < 4; ++e2)
      #pragma unroll
      for (int e1 = 0; e1 < 4; ++e1)
        buf[sA(pbase + (e2 << 4) + (e1 << 2))] = rb[(e2 << 2) + e1];
  }
  __syncthreads();
  {
    const int cbase = ((w >> 4) << 8) + (((w >> 2) & 3) << 6) + ((w & 3) << 4);
    #pragma unroll
    for (int e1 = 0; e1 < 4; ++e1)
      #pragma unroll
      for (int e0 = 0; e0 < 4; ++e0)
        rc[(e1 << 2) + e0] = buf[sA(cbase + (e1 << 2) + e0)];
    #pragma unroll
    for (int e1 = 0; e1 < 4; ++e1) {
      float2 x0 = rc[(e1 << 2)], x1 = rc[(e1 << 2) + 1], x2 = rc[(e1 << 2) + 2], x3 = rc[(e1 << 2) + 3];
      float2 a = cadd(x0, x2), b = csub(x0, x2);
      float2 c = cadd(x1, x3), d = cmuli(csub(x1, x3));
      rc[(e1 << 2)]     = cadd(a, c);
      rc[(e1 << 2) + 1] = cadd(b, d);
      rc[(e1 << 2) + 2] = csub(a, c);
      rc[(e1 << 2) + 3] = csub(b, d);
    }
  }
}

// ---- scalars helper ----------------------------------------------------------
__device__ inline float med8_dev(const float* p) {
  float v[8];
  for (int i = 0; i < 8; ++i) v[i] = p[i];
  for (int i = 1; i < 8; ++i) { float key = v[i]; int j = i - 1;
    while (j >= 0 && v[j] > key) { v[j + 1] = v[j]; --j; } v[j + 1] = key; }
  return 0.5f * (v[3] + v[4]);
}

// ---- merged: scalars (blk 960) + wsum (blk 0..511) + prep (blk 512..959) ----
__global__ __launch_bounds__(256) void k_misc(Hdr* h,
    const float* er, const float* ei, const float* ar, const float* ai,
    const float* pr, const float* pim,
    const float* __restrict__ w1, const float* __restrict__ w2,
    float2* __restrict__ wsum,
    unsigned short* __restrict__ A_E, unsigned short* __restrict__ B2T,
    unsigned short* __restrict__ ET, unsigned short* __restrict__ Fc,
    unsigned short* __restrict__ Fs, unsigned short* __restrict__ Fns) {
  const int b = blockIdx.x;
  if (b == 960) {
    if (threadIdx.x) return;
    float mer = med8_dev(er), mei = med8_dev(ei);
    h->e_r = mer; h->e_i = mei;
    h->amp_r = med8_dev(ar); h->amp_i = med8_dev(ai);
    h->phi_r = (int)med8_dev(pr);
    h->phi_i = (int)med8_dev(pim);
    h->nhe_r = -0.5f * mer; h->nhe_i = -0.5f * mei;
    return;
  }
  if (b < 512) {
    int idx = b * 256 + threadIdx.x;
    int sel = idx >> 16, rem = idx & 65535;
    const float* w = sel ? w2 : w1;
    int c = rem >> 10, m1 = (rem >> 5) & 31, m2 = rem & 31;
    size_t base = (size_t)c * 131072 + (size_t)m1 * 64 + (size_t)m2 * 2;
    float sr = 0.f, si = 0.f;
    for (int oc = 0; oc < 64; ++oc) { sr += w[base + (size_t)oc * 2048]; si += w[base + (size_t)oc * 2048 + 1]; }
    wsum[idx] = make_float2(sr, si);
    return;
  }
  int t = (b - 512) * 256 + threadIdx.x;
  if (t < 32768) {
    int y = t >> 7, p = t & 127;
    int kyp = p & 63; int ky = (kyp < 32) ? kyp : kyp + 192;
    float s, c; sincospif(2.0f * (float)((ky * y) & 255) * (1.0f / 256.0f), &s, &c);
    A_E[t] = f2bf((p < 64) ? c : s);
  } else if (t < 49152) {
    int u = t - 32768;
    int x = u >> 6, j = u & 63, kx = j & 31;
    float s, c; sincospif(2.0f * (float)((kx * x) & 255) * (1.0f / 256.0f), &s, &c);
    float v = (j < 32) ? ((kx == 0) ? 1.0f : 2.0f * c)
                       : ((kx == 0) ? 0.0f : -2.0f * s);
    B2T[u] = f2bf(v * (1.0f / 65536.0f));
  } else if (t < 65536) {
    int u = t - 49152;
    int col = u >> 8, xx = u & 255; int kx = col & 31;
    float s, c; sincospif(2.0f * (float)((kx * xx) & 255) * (1.0f / 256.0f), &s, &c);
    ET[u] = f2bf((col < 32) ? c : -s);
  } else if (t < 114688) {
    int u = (t - 65536) & 16383;
    int which = (t - 65536) >> 14;
    int kyp = u >> 8, y = u & 255; int ky = (kyp < 32) ? kyp : kyp + 192;
    float s, c; sincospif(2.0f * (float)((ky * y) & 255) * (1.0f / 256.0f), &s, &c);
    if (which == 0) Fc[u] = f2bf(c);
    else if (which == 1) Fs[u] = f2bf(s);
    else Fns[u] = f2bf(-s);
  }
}

// ---- merged: sumw2 (blk 0..511) + noise_spec (blk 512..4607) ----------------
__global__ __launch_bounds__(256) void k_gen(const Hdr* __restrict__ h,
                                             float* __restrict__ partials,
                                             float4* __restrict__ spT, KeyArgs ka) {
  __shared__ float sr_[256], si_[256];
  const int b = blockIdx.x;
  if (b < 512) {
    const float nher = h->nhe_r, nhei = h->nhe_i;
    float sr = 0.f, si = 0.f;
    for (int j = 0; j < 4; ++j) {
      uint32_t k = (uint32_t)(b * 1024 + j * 256 + threadIdx.x) + 1u;
      float fk = (float)k * (1.0f / 1048576.0f);
      float wr = powf(fk, nher), wi = powf(fk, nhei);
      if (k == NHALF) { wr *= 0.5f; wi *= 0.5f; }
      sr += wr * wr; si += wi * wi;
    }
    sr_[threadIdx.x] = sr; si_[threadIdx.x] = si; __syncthreads();
    for (int off = 128; off > 0; off >>= 1) {
      if ((int)threadIdx.x < off) { sr_[threadIdx.x] += sr_[threadIdx.x + off];
                                    si_[threadIdx.x] += si_[threadIdx.x + off]; }
      __syncthreads();
    }
    if (!threadIdx.x) { partials[b * 2] = sr_[0]; partials[b * 2 + 1] = si_[0]; }
    return;
  }
  const int idx = b - 512;
  const int pair = idx >> 11;
  const int bx = idx & 2047;
  const int k1 = bx >> 1, chunk = bx & 1;
  const int k2 = (chunk << 8) + (int)threadIdx.x;
  const float nher = h->nhe_r, nhei = h->nhe_i;
  float4* row = spT + (size_t)pair * (1024 * SPT_STRIDE) + (size_t)k1 * SPT_STRIDE;
  const bool extra = (k1 == 0) && (chunk == 1) && (threadIdx.x == 255);
  const int niter = extra ? 2 : 1;
  for (int it = 0; it < niter; ++it) {
    const int kk2 = (it == 0) ? k2 : 512;
    const uint32_t i = (uint32_t)k1 + ((uint32_t)kk2 << 10);
    float vals[4];
    #pragma unroll
    for (int j = 0; j < 4; ++j) {
      const uint32_t K0 = ka.k[pair * 4 + j][0], K1 = ka.k[pair * 4 + j][1];
      uint32_t o0, o1; tf2x32(K0, K1, 0u, i, o0, o1);
#if PART_XOR
      uint32_t bits = o0 ^ o1;
#else
      uint32_t bits = o1;
#endif
      float nhe = (j < 2) ? nher : nhei;
      float v = normal_from_bits(bits) * sscale_f(i, nhe);
      if (i == 0u || i == NHALF) v = (j & 1) ? 0.0f : v * 1.41421356f;
      vals[j] = v;
    }
    row[kk2] = make_float4(vals[0], vals[1], vals[2], vals[3]);
  }
}

__global__ void k_sumw2_fin(Hdr* h, const float* partials) {
  if (threadIdx.x || blockIdx.x) return;
  float Sr = 0.f, Si = 0.f;
  for (int b = 0; b < 512; ++b) { Sr += partials[b * 2]; Si += partials[b * 2 + 1]; }
  float sig_r = 2.0f * sqrtf(Sr) * (1.0f / 1048576.0f);
  float sig_i = 2.0f * sqrtf(Si) * (1.0f / 1048576.0f);
  float s0 = h->amp_r / (sig_r * 1048576.0f);
  float s1 = (h->amp_i * h->amp_i) / (sig_i * 1048576.0f);
  h->scale_s[0] = s0; h->scale_s[1] = s1; h->scale_s[2] = s0; h->scale_s[3] = s1;
}

// ---- irfft stage 1: complex-pair; G stored TRANSPOSED G[pair][j2][k1] -------
__global__ __launch_bounds__(256) void k_fft_s1(const float4* __restrict__ spT,
                                                float2* __restrict__ G) {
  __shared__ float2 buf4[4][1024];
  const int b = blockIdx.x;
  const int lin = (b & 7) * 64 + (b >> 3);
  const int pair = lin >> 8;
  const int g = threadIdx.x >> 6, w = threadIdx.x & 63;
  const int k1b = (lin & 255) << 2;
  const int k1 = k1b + g;
  const float4* sp = spT + (size_t)pair * (1024 * SPT_STRIDE);
  const int mrow = (1024 - k1) & 1023;

  float2 r[16], rc[16];
  #pragma unroll
  for (int s = 0; s < 16; ++s) {
    int k2 = (s << 6) + w;
    uint32_t k = (uint32_t)k1 + ((uint32_t)k2 << 10);
    float4 f; float2 z;
    if (k <= NHALF) {
      f = sp[(size_t)k1 * SPT_STRIDE + k2];
      z = make_float2(f.x - f.w, f.y + f.z);
    } else {
      int k2p = (k1 == 0) ? (1024 - k2) : (1023 - k2);
      f = sp[(size_t)mrow * SPT_STRIDE + k2p];
      z = make_float2(f.x + f.w, f.z - f.y);
    }
    r[s] = z;
  }
  fft1024_core(r, rc, buf4[g], w);
  // stash twiddled results back into this wave's buf (wave-private, no barrier)
  const int klo = ((w & 3) << 4) + (((w >> 2) & 3) << 2) + (w >> 4);
  #pragma unroll
  for (int e1 = 0; e1 < 4; ++e1)
    #pragma unroll
    for (int e0 = 0; e0 < 4; ++e0) {
      int k = (e0 << 8) + (e1 << 6) + klo;
      float2 tw = wexp((float)(k * k1) * (1.0f / 1048576.0f));
      buf4[g][sA(k)] = cmul(rc[(e1 << 2) + e0], tw);
    }
  __syncthreads();
  // cooperative transposed store: G[pair][j2][k1b + 0..3], 32B runs
  const int t = threadIdx.x;
  float2* gp = G + ((size_t)pair << 20) + (size_t)k1b;
  const int k1off = t & 3;
  #pragma unroll
  for (int it = 0; it < 16; ++it) {
    int j2 = (it << 6) + (t >> 2);
    gp[((size_t)j2 << 10) + k1off] = buf4[k1off][sA(j2)];
  }
}

// ---- stage 2: per j2, FFT over k1 (coalesced row reads of G[j2][k1]) --------
__global__ __launch_bounds__(256) void k_fft_s2(const float2* __restrict__ G,
                                                float2* __restrict__ noiseP,
                                                const Hdr* __restrict__ h) {
  __shared__ float2 buf4[4][1024];
  const int b = blockIdx.x;
  const int lin = (b & 7) * 64 + (b >> 3);
  const int pair = lin >> 8;
  const int g = threadIdx.x >> 6, w = threadIdx.x & 63;
  const int j2 = ((lin & 255) << 2) + g;

  float2 r[16], rc[16];
  const float2* gp = G + ((size_t)pair << 20) + ((size_t)j2 << 10);
  #pragma unroll
  for (int s = 0; s < 16; ++s) r[s] = gp[(s << 6) + w];
  fft1024_core(r, rc, buf4[g], w);
  const float scr = h->scale_s[0], sci = h->scale_s[1];
  float2* np_ = noiseP + ((size_t)pair << 20) + ((size_t)j2 << 10);
  const int klo = ((w & 3) << 4) + (((w >> 2) & 3) << 2) + (w >> 4);
  #pragma unroll
  for (int e1 = 0; e1 < 4; ++e1)
    #pragma unroll
    for (int e0 = 0; e0 < 4; ++e0) {
      int k = (e0 << 8) + (e1 << 6) + klo;
      np_[k] = make_float2(rc[(e1 << 2) + e0].x * scr, rc[(e1 << 2) + e0].y * sci);
    }
}

// ---- noise linearize: transpose 1024x1024 (pairs) + roll fold ---------------
__global__ __launch_bounds__(256) void k_ntrans(const float2* __restrict__ noiseP,
                                                float* __restrict__ noiseL,
                                                const Hdr* __restrict__ h) {
  __shared__ float tr[64][65];
  __shared__ float ti[64][65];
  const int b = blockIdx.x;
  const int pair = b >> 8, tid = b & 255;
  const int R0 = (tid >> 4) << 6;
  const int C0 = (tid & 15) << 6;
  const int t = threadIdx.x;
  const int tx = t & 63, ty = t >> 6;
  const int phir = h->phi_r, phii = h->phi_i;
  const float2* src = noiseP + ((size_t)pair << 20);
  float* dstr = noiseL + ((size_t)(pair * 2) << 20);
  float* dsti = noiseL + ((size_t)(pair * 2 + 1) << 20);
  #pragma unroll
  for (int i = 0; i < 16; ++i) {
    int r = (i << 2) + ty;
    float2 v = src[(size_t)((R0 + r) << 10) + (size_t)(C0 + tx)];
    tr[r][tx] = v.x; ti[r][tx] = v.y;
  }
  __syncthreads();
  #pragma unroll
  for (int i = 0; i < 16; ++i) {
    int c = (i << 2) + ty;
    int n = ((C0 + c) << 10) + R0 + tx;
    dstr[(uint32_t)(n + phir) & (N20 - 1u)] = tr[tx][c];
    dsti[(uint32_t)(n + phii) & (N20 - 1u)] = ti[tx][c];
  }
}

// ---- fwd1: x -> X1 (kx-DFT) only; 32KB LDS, high occupancy -------------------
// X1g layout: [bc][y 256][col 64] bf16 (coalesced 64B-run stores)
__global__ __launch_bounds__(256) void k_fwd1(const float* __restrict__ x,
    const unsigned short* __restrict__ ET, unsigned short* __restrict__ X1g) {
  __shared__ char lds[32768];
  const int bc = blockIdx.x, t = threadIdx.x;
  const int l = t & 63, w = t >> 6, lr = l & 31, kg = l >> 5;
  const int rt = w >> 1, ct = w & 1;
  const float* xim = x + ((size_t)bc << 16);
  unsigned short* xg = X1g + ((size_t)bc << 14);

  float4 pf[16];
  #pragma unroll
  for (int i = 0; i < 16; ++i) {
    int f4 = i * 256 + t;
    int r = f4 >> 6, c4 = f4 & 63;
    pf[i] = *(const float4*)(xim + (size_t)((r) << 8) + (c4 << 2));
  }

  #pragma unroll
  for (int yt = 0; yt < 4; ++yt) {
    __syncthreads();
    #pragma unroll
    for (int i = 0; i < 16; ++i) {
      int f4 = i * 256 + t;
      int r = f4 >> 6, c4 = f4 & 63;
      ushort4 b4; b4.x = f2bf(pf[i].x); b4.y = f2bf(pf[i].y);
      b4.z = f2bf(pf[i].z); b4.w = f2bf(pf[i].w);
      int byte = ((r << 9) + (c4 << 3)) ^ ((r & 7) << 4);
      *(ushort4*)(lds + byte) = b4;
    }
    __syncthreads();
    if (yt < 3) {
      #pragma unroll
      for (int i = 0; i < 16; ++i) {
        int f4 = i * 256 + t;
        int r = f4 >> 6, c4 = f4 & 63;
        pf[i] = *(const float4*)(xim + (size_t)((((yt + 1) << 6) + r) << 8) + (c4 << 2));
      }
    }
    f32x16 a1 = zero16();
    const int arow = (rt << 5) + lr;
    const int bcol = (ct << 5) + lr;
    #pragma unroll
    for (int s = 0; s < 16; ++s) {
      short8 af = *(const short8*)(lds + (((arow << 9) + (s << 5) + (kg << 4)) ^ ((arow & 7) << 4)));
      short8 bf = *(const short8*)(ET + (bcol << 8) + (s << 4) + (kg << 3));
      a1 = __builtin_amdgcn_mfma_f32_32x32x16_bf16(af, bf, a1, 0, 0, 0);
    }
    // store to X1g[y][col]: reg i -> y = yt*64 + rt*32 + 8*(i>>2) + 4*kg + (i&3)
    #pragma unroll
    for (int i = 0; i < 16; ++i) {
      int y = (yt << 6) + (rt << 5) + ((i >> 2) << 3) + (kg << 2) + (i & 3);
      xg[(y << 6) + bcol] = f2bf(a1[i]);
    }
  }
}

// ---- fwd2: X1 -> O (ky-DFT) + wsum mul + noise subtract -> oft ---------------
__global__ __launch_bounds__(256) void k_fwd2(const unsigned short* __restrict__ X1g,
    const float2* __restrict__ wsum, const float* __restrict__ noiseL,
    const unsigned short* __restrict__ Fc, const unsigned short* __restrict__ Fs,
    const unsigned short* __restrict__ Fns, float2* __restrict__ oftg) {
  __shared__ char X1T[32768];   // [col][y] bf16 swizzled; reused for Osm after
  const int bc = blockIdx.x, t = threadIdx.x;
  const int c = bc & 63;
  const int l = t & 63, w = t >> 6, lr = l & 31, kg = l >> 5;

  // stage X1 [y][col] -> X1T [col][y] swizzled
  {
    const unsigned short* xg = X1g + ((size_t)bc << 14);
    #pragma unroll
    for (int i = 0; i < 8; ++i) {
      int e = i * 2048 + t * 8;
      int y = e >> 6, col0 = e & 63;
      ushort4 v0 = *(const ushort4*)(xg + e);
      ushort4 v1 = *(const ushort4*)(xg + e + 4);
      unsigned short vv[8] = { v0.x, v0.y, v0.z, v0.w, v1.x, v1.y, v1.z, v1.w };
      #pragma unroll
      for (int j = 0; j < 8; ++j) {
        int col = col0 + j;
        int byte = ((col << 9) + (y << 1)) ^ ((col & 7) << 4);
        *(unsigned short*)(X1T + byte) = vv[j];
      }
    }
  }
  __syncthreads();

  const int re_im = w >> 1, kt = w & 1;
  const unsigned short* A1p = re_im ? Fns : Fs;
  const int b0row = (re_im ? 32 : 0) + lr;
  const int b1row = (re_im ? 0 : 32) + lr;
  const int a2row = (kt << 5) + lr;
  f32x16 a2 = zero16();
  #pragma unroll
  for (int s = 0; s < 16; ++s) {
    short8 a0f = *(const short8*)(Fc  + (a2row << 8) + (s << 4) + (kg << 3));
    short8 a1f = *(const short8*)(A1p + (a2row << 8) + (s << 4) + (kg << 3));
    short8 b0f = *(const short8*)(X1T + (((b0row << 9) + (s << 5) + (kg << 4)) ^ ((b0row & 7) << 4)));
    short8 b1f = *(const short8*)(X1T + (((b1row << 9) + (s << 5) + (kg << 4)) ^ ((b1row & 7) << 4)));
    a2 = __builtin_amdgcn_mfma_f32_32x32x16_bf16(a0f, b0f, a2, 0, 0, 0);
    a2 = __builtin_amdgcn_mfma_f32_32x32x16_bf16(a1f, b1f, a2, 0, 0, 0);
  }
  __syncthreads();   // all X1T reads done before Osm overwrites
  float* Osm = (float*)(X1T + (re_im << 13));  // re @0, im @8192
  #pragma unroll
  for (int i = 0; i < 16; ++i) {
    int row = (kt << 5) + (i & 3) + ((i >> 2) << 3) + (kg << 2);
    Osm[(row << 5) + lr] = a2[i];
  }
  __syncthreads();

  const float* Ore = (const float*)X1T;
  const float* Oim = (const float*)(X1T + 8192);
  #pragma unroll
  for (int r = 0; r < 8; ++r) {
    int idx = (r << 8) + t;
    int kyp = idx >> 5, kx = idx & 31;
    int sel = kyp >> 5, m1 = kyp & 31;
    float2 av = make_float2(Ore[idx], Oim[idx]);
    float2 wv = wsum[((size_t)sel << 16) + (size_t)(((c << 5) | m1) << 5) + (size_t)kx];
    float2 v;
    v.x = av.x * wv.x - av.y * wv.y;
    v.y = av.x * wv.y + av.y * wv.x;
    uint32_t p = ((uint32_t)((bc << 5) | m1) << 5) | (uint32_t)kx;
    const float* nlr = noiseL + ((size_t)(sel ? 2 : 0) << 20);
    const float* nli = noiseL + ((size_t)(sel ? 3 : 1) << 20);
    v.x -= nlr[p];
    v.y -= nli[p];
    oftg[((size_t)bc << 11) + (size_t)idx] = v;
  }
}

// ---- inverse via two bf16 MFMA GEMMs per image (32KB LDS) --------------------
__global__ __launch_bounds__(256) void k_inverse(const float2* __restrict__ oftg,
    const unsigned short* __restrict__ A_E, const unsigned short* __restrict__ B2T,
    float* __restrict__ out) {
  __shared__ char smem[32768];

  const int bc = blockIdx.x, t = threadIdx.x;
  const int l = t & 63, w = t >> 6, lr = l & 31, kg = l >> 5;

  {
    const float* ob = (const float*)(oftg + ((size_t)bc << 11));
    #pragma unroll
    for (int i = 0; i < 32; ++i) {
      int idx = t + (i << 8);
      int p = idx >> 6, j = idx & 63;
      int kyp = p & 63;
      float v;
      if (p < 64) v = (j < 32) ? ob[(kyp << 6) + (j << 1)]
                               : ob[(kyp << 6) + ((j - 32) << 1) + 1];
      else        v = (j < 32) ? -ob[(kyp << 6) + (j << 1) + 1]
                               : ob[(kyp << 6) + ((j - 32) << 1)];
      int byte = ((j << 8) + (p << 1)) ^ ((j & 7) << 4);
      *(unsigned short*)(smem + byte) = f2bf(v);
    }
  }
  __syncthreads();

  f32x16 acc[2][2];
  acc[0][0] = zero16(); acc[0][1] = zero16(); acc[1][0] = zero16(); acc[1][1] = zero16();
  #pragma unroll
  for (int s = 0; s < 8; ++s) {
    short8 af[2], bf[2];
    #pragma unroll
    for (int rt = 0; rt < 2; ++rt) {
      int row = (w << 6) + (rt << 5) + lr;
      af[rt] = *(const short8*)(A_E + (row << 7) + (s << 4) + (kg << 3));
    }
    #pragma unroll
    for (int ct = 0; ct < 2; ++ct) {
      int j = (ct << 5) + lr;
      int byte = ((j << 8) + (s << 5) + (kg << 4)) ^ ((j & 7) << 4);
      bf[ct] = *(const short8*)(smem + byte);
    }
    #pragma unroll
    for (int rt = 0; rt < 2; ++rt)
      #pragma unroll
      for (int ct = 0; ct < 2; ++ct)
        acc[rt][ct] = __builtin_amdgcn_mfma_f32_32x32x16_bf16(af[rt], bf[ct], acc[rt][ct], 0, 0, 0);
  }
  __syncthreads();

  #pragma unroll
  for (int rt = 0; rt < 2; ++rt)
    #pragma unroll
    for (int ct = 0; ct < 2; ++ct)
      #pragma unroll
      for (int r = 0; r < 16; ++r) {
        int row = (w << 6) + (rt << 5) + (r & 3) + (((r >> 2) & 3) << 3) + (kg << 2);
        int col = (ct << 5) + lr;
        int byte = ((row << 7) + (col << 1)) ^ ((row & 7) << 4);
        *(unsigned short*)(smem + byte) = f2bf(acc[rt][ct][r]);
      }
  __syncthreads();

  short8 ta[2][4];
  #pragma unroll
  for (int rt = 0; rt < 2; ++rt)
    #pragma unroll
    for (int ks = 0; ks < 4; ++ks) {
      int row = (w << 6) + (rt << 5) + lr;
      int byte = ((row << 7) + (ks << 5) + (kg << 4)) ^ ((row & 7) << 4);
      ta[rt][ks] = *(const short8*)(smem + byte);
    }
  float* op = out + ((size_t)bc << 16);
  #pragma unroll
  for (int cc = 0; cc < 4; ++cc) {
    short8 b2[2][4];
    #pragma unroll
    for (int cx = 0; cx < 2; ++cx)
      #pragma unroll
      for (int ks = 0; ks < 4; ++ks) {
        int xx = (cc << 6) + (cx << 5) + lr;
        b2[cx][ks] = *(const short8*)(B2T + (xx << 6) + (ks << 4) + (kg << 3));
      }
    f32x16 a2[2][2];
    a2[0][0] = zero16(); a2[0][1] = zero16(); a2[1][0] = zero16(); a2[1][1] = zero16();
    #pragma unroll
    for (int ks = 0; ks < 4; ++ks)
      #pragma unroll
      for (int rt = 0; rt < 2; ++rt)
        #pragma unroll
        for (int cx = 0; cx < 2; ++cx)
          a2[rt][cx] = __builtin_amdgcn_mfma_f32_32x32x16_bf16(ta[rt][ks], b2[cx][ks], a2[rt][cx], 0, 0, 0);
    #pragma unroll
    for (int rt = 0; rt < 2; ++rt)
      #pragma unroll
      for (int cx = 0; cx < 2; ++cx)
        #pragma unroll
        for (int r = 0; r < 16; ++r) {
          int row = (w << 6) + (rt << 5) + (r & 3) + (((r >> 2) & 3) << 3) + (kg << 2);
          int xx = (cc << 6) + (cx << 5) + lr;
          op[(row << 8) + xx] = a2[rt][cx][r];
        }
  }
}

// ---- host -------------------------------------------------------------------
extern "C" void kernel_launch(void* const* d_in, const int* in_sizes, int n_in,
                              void* d_out, int out_size, void* d_ws, size_t ws_size,
                              hipStream_t stream) {
  (void)in_sizes; (void)n_in; (void)out_size; (void)ws_size;
  const float* x   = (const float*)d_in[0];
  const float* w1  = (const float*)d_in[1];
  const float* w2  = (const float*)d_in[2];
  const float* er  = (const float*)d_in[3];
  const float* ei  = (const float*)d_in[4];
  const float* ar  = (const float*)d_in[5];
  const float* ai  = (const float*)d_in[6];
  const float* pr  = (const float*)d_in[7];
  const float* pim = (const float*)d_in[8];
  float* out = (float*)d_out;

  char* ws = (char*)d_ws;
  Hdr*    hdr      = (Hdr*)ws;
  float*  partials = (float*)(ws + 0x1000);
  float2* wsum     = (float2*)(ws + 0x10000);
  unsigned short* A_E = (unsigned short*)(ws + 0x130000);
  unsigned short* B2T = (unsigned short*)(ws + 0x140000);
  unsigned short* ET  = (unsigned short*)(ws + 0x148000);
  unsigned short* Fc  = (unsigned short*)(ws + 0x150000);
  unsigned short* Fs  = (unsigned short*)(ws + 0x158000);
  unsigned short* Fns = (unsigned short*)(ws + 0x160000);
  float4* spT      = (float4*)(ws + 0x200000);    // ~17MB; dead after fft_s1
  float2* G        = (float2*)(ws + 0x1400000);   // 16MB; dead after fft_s2
  unsigned short* X1g = (unsigned short*)(ws + 0x200000); // 32MB over spT+G (both dead)
  float2* oft      = (float2*)(ws + 0x2400000);   // 16MB over noiseP (dead after ntrans)
  float2* noiseP   = (float2*)(ws + 0x2400000);   // 16MB
  float*  noiseL   = (float*)(ws + 0x3400000);    // 16MB; total ws = 68MB

  auto splitk = [](const uint32_t k[2], uint32_t a[2], uint32_t b[2]) {
#if JPART
    tf2x32(k[0], k[1], 0u, 0u, a[0], a[1]);
    tf2x32(k[0], k[1], 0u, 1u, b[0], b[1]);
#else
    uint32_t r0[2], r1[2];
    tf2x32(k[0], k[1], 0u, 2u, r0[0], r0[1]);
    tf2x32(k[0], k[1], 1u, 3u, r1[0], r1[1]);
    a[0] = r0[0]; a[1] = r1[0]; b[0] = r0[1]; b[1] = r1[1];
#endif
  };
  uint32_t root[2] = { 0u, 42u };
  uint32_t kA[2], kB[2], k1A[2], k2A[2], k1B[2], k2B[2];
  splitk(root, kA, kB);
  splitk(kA, k1A, k2A);
  splitk(kB, k1B, k2B);
  KeyArgs ka;
  splitk(k1A, ka.k[0], ka.k[1]);
  splitk(k2A, ka.k[2], ka.k[3]);
  splitk(k1B, ka.k[4], ka.k[5]);
  splitk(k2B, ka.k[6], ka.k[7]);

  hipLaunchKernelGGL(k_misc,      dim3(961),      dim3(256), 0, stream, hdr, er, ei, ar, ai, pr, pim,
                     w1, w2, wsum, A_E, B2T, ET, Fc, Fs, Fns);
  hipLaunchKernelGGL(k_gen,       dim3(4608),     dim3(256), 0, stream, hdr, partials, spT, ka);
  hipLaunchKernelGGL(k_sumw2_fin, dim3(1),        dim3(64),  0, stream, hdr, partials);
  hipLaunchKernelGGL(k_fft_s1,    dim3(512),      dim3(256), 0, stream, spT, G);
  hipLaunchKernelGGL(k_fft_s2,    dim3(512),      dim3(256), 0, stream, G, noiseP, hdr);
  hipLaunchKernelGGL(k_ntrans,    dim3(512),      dim3(256), 0, stream, noiseP, noiseL, hdr);
  hipLaunchKernelGGL(k_fwd1,      dim3(1024),     dim3(256), 0, stream, x, ET, X1g);
  hipLaunchKernelGGL(k_fwd2,      dim3(1024),     dim3(256), 0, stream, X1g, wsum, noiseL, Fc, Fs, Fns, oft);
  hipLaunchKernelGGL(k_inverse,   dim3(1024),     dim3(256), 0, stream, oft, A_E, B2T, out);
}

// Round 13
// 264.028 us; speedup vs baseline: 1.0429x; 1.0429x over previous
//
#include <hip/hip_runtime.h>
#include <cstdint>

// ---- JAX PRNG mode switches -------------------------------------------------
#define JPART 1
#define PART_XOR 1

constexpr uint32_t N20   = 1u << 20;
constexpr uint32_t NHALF = 1u << 19;
constexpr int SPT_STRIDE = 520;   // padded row stride (float4 elems) for spT

struct Hdr {
  float e_r, e_i, amp_r, amp_i;
  int   phi_r, phi_i;
  float nhe_r, nhe_i;
  float scale_s[4];
};
struct KeyArgs { uint32_t k[8][2]; };

typedef __attribute__((ext_vector_type(8))) short short8;
typedef __attribute__((ext_vector_type(16))) float f32x16;

__device__ inline f32x16 zero16() {
  f32x16 v;
  #pragma unroll
  for (int i = 0; i < 16; ++i) v[i] = 0.f;
  return v;
}

__device__ inline unsigned short f2bf(float f) {
  uint32_t u = __float_as_uint(f);
  return (unsigned short)((u + 0x7fffu + ((u >> 16) & 1u)) >> 16);
}

// ---- Threefry2x32-20 (exact JAX cipher) ------------------------------------
__host__ __device__ inline void tf2x32(uint32_t k0, uint32_t k1, uint32_t x0, uint32_t x1,
                                       uint32_t& o0, uint32_t& o1) {
  const uint32_t ks0 = k0, ks1 = k1, ks2 = k0 ^ k1 ^ 0x1BD11BDAu;
  const uint32_t ks[3] = { ks0, ks1, ks2 };
  x0 += ks0; x1 += ks1;
  const int rot[2][4] = { {13,15,26,6}, {17,29,16,24} };
  for (int g = 0; g < 5; ++g) {
    const int* rr = rot[g & 1];
    for (int i = 0; i < 4; ++i) {
      x0 += x1;
      x1 = (x1 << rr[i]) | (x1 >> (32 - rr[i]));
      x1 ^= x0;
    }
    x0 += ks[(g + 1) % 3];
    x1 += ks[(g + 2) % 3] + (uint32_t)(g + 1);
  }
  o0 = x0; o1 = x1;
}

// ---- XLA ErfInv32 polynomial ------------------------------------------------
__device__ inline float erfinv_xla(float x) {
  float w = -log1pf(-x * x);
  float p;
  if (w < 5.0f) {
    w -= 2.5f;
    p = 2.81022636e-08f;
    p = fmaf(p, w, 3.43273939e-07f);
    p = fmaf(p, w, -3.5233877e-06f);
    p = fmaf(p, w, -4.39150654e-06f);
    p = fmaf(p, w, 0.00021858087f);
    p = fmaf(p, w, -0.00125372503f);
    p = fmaf(p, w, -0.00417768164f);
    p = fmaf(p, w, 0.246640727f);
    p = fmaf(p, w, 1.50140941f);
  } else {
    w = sqrtf(w) - 3.0f;
    p = -0.000200214257f;
    p = fmaf(p, w, 0.000100950558f);
    p = fmaf(p, w, 0.00134934322f);
    p = fmaf(p, w, -0.00367342844f);
    p = fmaf(p, w, 0.00573950773f);
    p = fmaf(p, w, -0.0076224613f);
    p = fmaf(p, w, 0.00943887047f);
    p = fmaf(p, w, 1.00167406f);
    p = fmaf(p, w, 2.83297682f);
  }
  return p * x;
}

__device__ inline float normal_from_bits(uint32_t bits) {
  uint32_t fb = (bits >> 9) | 0x3f800000u;
  float f = __uint_as_float(fb) - 1.0f;
  const float LO = -0.99999994f;
  float u = f * 2.0f + LO;
  u = fmaxf(LO, u);
  return 1.41421356f * erfinv_xla(u);
}

__device__ inline float sscale_f(uint32_t k, float nhe) {
  uint32_t kk = k ? k : 1u;
  return powf((float)kk * (1.0f / 1048576.0f), nhe);
}

__device__ inline float2 cmul(float2 a, float2 b) {
  return make_float2(a.x * b.x - a.y * b.y, a.x * b.y + a.y * b.x);
}
__device__ inline float2 wexp(float u) {
  float s, c; sincospif(2.0f * u, &s, &c); return make_float2(c, s);
}
__device__ inline float2 cadd(float2 a, float2 b){ return make_float2(a.x+b.x, a.y+b.y); }
__device__ inline float2 csub(float2 a, float2 b){ return make_float2(a.x-b.x, a.y-b.y); }
__device__ inline float2 cmuli(float2 a){ return make_float2(-a.y, a.x); }  // * (+i)

// LDS address swizzle for the FFT exchanges: <=4-way on all phases
__device__ inline int sA(int p) { return p ^ (((p >> 6) & 3) << 2) ^ ((p >> 8) & 3); }

// radix-4 DIF butterfly, sign +i, with twiddle W = omega^{n'}
__device__ inline void bfly(float2& y0, float2& y1, float2& y2, float2& y3, float2 W) {
  float2 a = cadd(y0, y2), b = csub(y0, y2);
  float2 c = cadd(y1, y3), d = cmuli(csub(y1, y3));
  float2 W2 = cmul(W, W), W3 = cmul(W2, W);
  y0 = cadd(a, c);
  y1 = cmul(cadd(b, d), W);
  y2 = cmul(csub(a, c), W2);
  y3 = cmul(csub(b, d), W3);
}

// 1024-pt FFT core (sign +), 64 threads, 16 pts/thread, 2 barriers.
__device__ inline void fft1024_core(float2* r, float2* rc, float2* buf, int w) {
  #pragma unroll
  for (int e3 = 0; e3 < 4; ++e3) {
    float2 W = wexp((float)((e3 << 6) + w) * (1.0f / 1024.0f));
    bfly(r[e3], r[e3 + 4], r[e3 + 8], r[e3 + 12], W);
  }
  {
    float2 W = wexp((float)w * (1.0f / 256.0f));
    #pragma unroll
    for (int e4 = 0; e4 < 4; ++e4)
      bfly(r[(e4 << 2) + 0], r[(e4 << 2) + 1], r[(e4 << 2) + 2], r[(e4 << 2) + 3], W);
  }
  #pragma unroll
  for (int s = 0; s < 16; ++s) buf[sA((s << 6) + w)] = r[s];
  __syncthreads();
  {
    const int e0 = w & 3;
    const int pbase = ((w >> 4) << 8) + (((w >> 2) & 3) << 6) + e0;
    float2 rb[16];
    #pragma unroll
    for (int e2 = 0; e2 < 4; ++e2)
      #pragma unroll
      for (int e1 = 0; e1 < 4; ++e1)
        rb[(e2 << 2) + e1] = buf[sA(pbase + (e2 << 4) + (e1 << 2))];
    #pragma unroll
    for (int e1 = 0; e1 < 4; ++e1) {
      float2 W = wexp((float)((e1 << 2) + e0) * (1.0f / 64.0f));
      bfly(rb[e1], rb[e1 + 4], rb[e1 + 8], rb[e1 + 12], W);
    }
    {
      float2 W = wexp((float)e0 * (1.0f / 16.0f));
      #pragma unroll
      for (int e2 = 0; e2 < 4; ++e2)
        bfly(rb[(e2 << 2) + 0], rb[(e2 << 2) + 1], rb[(e2 << 2) + 2], rb[(e2 << 2) + 3], W);
    }
    #pragma unroll
    for (int e2 = 0; e2 < 4; ++e2)
      #pragma unroll
      for (int e1 = 0; e1 < 4; ++e1)
        buf[sA(pbase + (e2 << 4) + (e1 << 2))] = rb[(e2 << 2) + e1];
  }
  __syncthreads();
  {
    const int cbase = ((w >> 4) << 8) + (((w >> 2) & 3) << 6) + ((w & 3) << 4);
    #pragma unroll
    for (int e1 = 0; e1 < 4; ++e1)
      #pragma unroll
      for (int e0 = 0; e0 < 4; ++e0)
        rc[(e1 << 2) + e0] = buf[sA(cbase + (e1 << 2) + e0)];
    #pragma unroll
    for (int e1 = 0; e1 < 4; ++e1) {
      float2 x0 = rc[(e1 << 2)], x1 = rc[(e1 << 2) + 1], x2 = rc[(e1 << 2) + 2], x3 = rc[(e1 << 2) + 3];
      float2 a = cadd(x0, x2), b = csub(x0, x2);
      float2 c = cadd(x1, x3), d = cmuli(csub(x1, x3));
      rc[(e1 << 2)]     = cadd(a, c);
      rc[(e1 << 2) + 1] = cadd(b, d);
      rc[(e1 << 2) + 2] = csub(a, c);
      rc[(e1 << 2) + 3] = csub(b, d);
    }
  }
}

// ---- scalars helper ----------------------------------------------------------
__device__ inline float med8_dev(const float* p) {
  float v[8];
  for (int i = 0; i < 8; ++i) v[i] = p[i];
  for (int i = 1; i < 8; ++i) { float key = v[i]; int j = i - 1;
    while (j >= 0 && v[j] > key) { v[j + 1] = v[j]; --j; } v[j + 1] = key; }
  return 0.5f * (v[3] + v[4]);
}

// ---- merged: scalars (blk 960) + wsum (blk 0..511) + prep (blk 512..959) ----
__global__ __launch_bounds__(256) void k_misc(Hdr* h,
    const float* er, const float* ei, const float* ar, const float* ai,
    const float* pr, const float* pim,
    const float* __restrict__ w1, const float* __restrict__ w2,
    float2* __restrict__ wsum,
    unsigned short* __restrict__ A_E, unsigned short* __restrict__ B2T,
    unsigned short* __restrict__ ET, unsigned short* __restrict__ Fc,
    unsigned short* __restrict__ Fs, unsigned short* __restrict__ Fns) {
  const int b = blockIdx.x;
  if (b == 960) {
    if (threadIdx.x) return;
    float mer = med8_dev(er), mei = med8_dev(ei);
    h->e_r = mer; h->e_i = mei;
    h->amp_r = med8_dev(ar); h->amp_i = med8_dev(ai);
    h->phi_r = (int)med8_dev(pr);
    h->phi_i = (int)med8_dev(pim);
    h->nhe_r = -0.5f * mer; h->nhe_i = -0.5f * mei;
    return;
  }
  if (b < 512) {
    int idx = b * 256 + threadIdx.x;
    int sel = idx >> 16, rem = idx & 65535;
    const float* w = sel ? w2 : w1;
    int c = rem >> 10, m1 = (rem >> 5) & 31, m2 = rem & 31;
    size_t base = (size_t)c * 131072 + (size_t)m1 * 64 + (size_t)m2 * 2;
    float sr = 0.f, si = 0.f;
    for (int oc = 0; oc < 64; ++oc) { sr += w[base + (size_t)oc * 2048]; si += w[base + (size_t)oc * 2048 + 1]; }
    wsum[idx] = make_float2(sr, si);
    return;
  }
  int t = (b - 512) * 256 + threadIdx.x;
  if (t < 32768) {
    int y = t >> 7, p = t & 127;
    int kyp = p & 63; int ky = (kyp < 32) ? kyp : kyp + 192;
    float s, c; sincospif(2.0f * (float)((ky * y) & 255) * (1.0f / 256.0f), &s, &c);
    A_E[t] = f2bf((p < 64) ? c : s);
  } else if (t < 49152) {
    int u = t - 32768;
    int x = u >> 6, j = u & 63, kx = j & 31;
    float s, c; sincospif(2.0f * (float)((kx * x) & 255) * (1.0f / 256.0f), &s, &c);
    float v = (j < 32) ? ((kx == 0) ? 1.0f : 2.0f * c)
                       : ((kx == 0) ? 0.0f : -2.0f * s);
    B2T[u] = f2bf(v * (1.0f / 65536.0f));
  } else if (t < 65536) {
    int u = t - 49152;
    int col = u >> 8, xx = u & 255; int kx = col & 31;
    float s, c; sincospif(2.0f * (float)((kx * xx) & 255) * (1.0f / 256.0f), &s, &c);
    ET[u] = f2bf((col < 32) ? c : -s);
  } else if (t < 114688) {
    int u = (t - 65536) & 16383;
    int which = (t - 65536) >> 14;
    int kyp = u >> 8, y = u & 255; int ky = (kyp < 32) ? kyp : kyp + 192;
    float s, c; sincospif(2.0f * (float)((ky * y) & 255) * (1.0f / 256.0f), &s, &c);
    if (which == 0) Fc[u] = f2bf(c);
    else if (which == 1) Fs[u] = f2bf(s);
    else Fns[u] = f2bf(-s);
  }
}

// ---- merged: sumw2 (blk 0..511) + noise_spec (blk 512..4607) ----------------
__global__ __launch_bounds__(256) void k_gen(const Hdr* __restrict__ h,
                                             float* __restrict__ partials,
                                             float4* __restrict__ spT, KeyArgs ka) {
  __shared__ float sr_[256], si_[256];
  const int b = blockIdx.x;
  if (b < 512) {
    const float nher = h->nhe_r, nhei = h->nhe_i;
    float sr = 0.f, si = 0.f;
    for (int j = 0; j < 4; ++j) {
      uint32_t k = (uint32_t)(b * 1024 + j * 256 + threadIdx.x) + 1u;
      float fk = (float)k * (1.0f / 1048576.0f);
      float wr = powf(fk, nher), wi = powf(fk, nhei);
      if (k == NHALF) { wr *= 0.5f; wi *= 0.5f; }
      sr += wr * wr; si += wi * wi;
    }
    sr_[threadIdx.x] = sr; si_[threadIdx.x] = si; __syncthreads();
    for (int off = 128; off > 0; off >>= 1) {
      if ((int)threadIdx.x < off) { sr_[threadIdx.x] += sr_[threadIdx.x + off];
                                    si_[threadIdx.x] += si_[threadIdx.x + off]; }
      __syncthreads();
    }
    if (!threadIdx.x) { partials[b * 2] = sr_[0]; partials[b * 2 + 1] = si_[0]; }
    return;
  }
  const int idx = b - 512;
  const int pair = idx >> 11;
  const int bx = idx & 2047;
  const int k1 = bx >> 1, chunk = bx & 1;
  const int k2 = (chunk << 8) + (int)threadIdx.x;
  const float nher = h->nhe_r, nhei = h->nhe_i;
  float4* row = spT + (size_t)pair * (1024 * SPT_STRIDE) + (size_t)k1 * SPT_STRIDE;
  const bool extra = (k1 == 0) && (chunk == 1) && (threadIdx.x == 255);
  const int niter = extra ? 2 : 1;
  for (int it = 0; it < niter; ++it) {
    const int kk2 = (it == 0) ? k2 : 512;
    const uint32_t i = (uint32_t)k1 + ((uint32_t)kk2 << 10);
    float vals[4];
    #pragma unroll
    for (int j = 0; j < 4; ++j) {
      const uint32_t K0 = ka.k[pair * 4 + j][0], K1 = ka.k[pair * 4 + j][1];
      uint32_t o0, o1; tf2x32(K0, K1, 0u, i, o0, o1);
#if PART_XOR
      uint32_t bits = o0 ^ o1;
#else
      uint32_t bits = o1;
#endif
      float nhe = (j < 2) ? nher : nhei;
      float v = normal_from_bits(bits) * sscale_f(i, nhe);
      if (i == 0u || i == NHALF) v = (j & 1) ? 0.0f : v * 1.41421356f;
      vals[j] = v;
    }
    row[kk2] = make_float4(vals[0], vals[1], vals[2], vals[3]);
  }
}

__global__ void k_sumw2_fin(Hdr* h, const float* partials) {
  if (threadIdx.x || blockIdx.x) return;
  float Sr = 0.f, Si = 0.f;
  for (int b = 0; b < 512; ++b) { Sr += partials[b * 2]; Si += partials[b * 2 + 1]; }
  float sig_r = 2.0f * sqrtf(Sr) * (1.0f / 1048576.0f);
  float sig_i = 2.0f * sqrtf(Si) * (1.0f / 1048576.0f);
  float s0 = h->amp_r / (sig_r * 1048576.0f);
  float s1 = (h->amp_i * h->amp_i) / (sig_i * 1048576.0f);
  h->scale_s[0] = s0; h->scale_s[1] = s1; h->scale_s[2] = s0; h->scale_s[3] = s1;
}

// ---- irfft stage 1: complex-pair; G stored TRANSPOSED G[pair][j2][k1] -------
__global__ __launch_bounds__(256) void k_fft_s1(const float4* __restrict__ spT,
                                                float2* __restrict__ G) {
  __shared__ float2 buf4[4][1024];
  const int b = blockIdx.x;
  const int lin = (b & 7) * 64 + (b >> 3);
  const int pair = lin >> 8;
  const int g = threadIdx.x >> 6, w = threadIdx.x & 63;
  const int k1b = (lin & 255) << 2;
  const int k1 = k1b + g;
  const float4* sp = spT + (size_t)pair * (1024 * SPT_STRIDE);
  const int mrow = (1024 - k1) & 1023;

  float2 r[16], rc[16];
  #pragma unroll
  for (int s = 0; s < 16; ++s) {
    int k2 = (s << 6) + w;
    uint32_t k = (uint32_t)k1 + ((uint32_t)k2 << 10);
    float4 f; float2 z;
    if (k <= NHALF) {
      f = sp[(size_t)k1 * SPT_STRIDE + k2];
      z = make_float2(f.x - f.w, f.y + f.z);
    } else {
      int k2p = (k1 == 0) ? (1024 - k2) : (1023 - k2);
      f = sp[(size_t)mrow * SPT_STRIDE + k2p];
      z = make_float2(f.x + f.w, f.z - f.y);
    }
    r[s] = z;
  }
  fft1024_core(r, rc, buf4[g], w);
  // stash twiddled results back into this wave's buf (wave-private, no barrier)
  const int klo = ((w & 3) << 4) + (((w >> 2) & 3) << 2) + (w >> 4);
  #pragma unroll
  for (int e1 = 0; e1 < 4; ++e1)
    #pragma unroll
    for (int e0 = 0; e0 < 4; ++e0) {
      int k = (e0 << 8) + (e1 << 6) + klo;
      float2 tw = wexp((float)(k * k1) * (1.0f / 1048576.0f));
      buf4[g][sA(k)] = cmul(rc[(e1 << 2) + e0], tw);
    }
  __syncthreads();
  // cooperative transposed store: G[pair][j2][k1b + 0..3], 32B runs
  const int t = threadIdx.x;
  float2* gp = G + ((size_t)pair << 20) + (size_t)k1b;
  const int k1off = t & 3;
  #pragma unroll
  for (int it = 0; it < 16; ++it) {
    int j2 = (it << 6) + (t >> 2);
    gp[((size_t)j2 << 10) + k1off] = buf4[k1off][sA(j2)];
  }
}

// ---- stage 2: per j2, FFT over k1 (coalesced row reads of G[j2][k1]) --------
__global__ __launch_bounds__(256) void k_fft_s2(const float2* __restrict__ G,
                                                float2* __restrict__ noiseP,
                                                const Hdr* __restrict__ h) {
  __shared__ float2 buf4[4][1024];
  const int b = blockIdx.x;
  const int lin = (b & 7) * 64 + (b >> 3);
  const int pair = lin >> 8;
  const int g = threadIdx.x >> 6, w = threadIdx.x & 63;
  const int j2 = ((lin & 255) << 2) + g;

  float2 r[16], rc[16];
  const float2* gp = G + ((size_t)pair << 20) + ((size_t)j2 << 10);
  #pragma unroll
  for (int s = 0; s < 16; ++s) r[s] = gp[(s << 6) + w];
  fft1024_core(r, rc, buf4[g], w);
  const float scr = h->scale_s[0], sci = h->scale_s[1];
  float2* np_ = noiseP + ((size_t)pair << 20) + ((size_t)j2 << 10);
  const int klo = ((w & 3) << 4) + (((w >> 2) & 3) << 2) + (w >> 4);
  #pragma unroll
  for (int e1 = 0; e1 < 4; ++e1)
    #pragma unroll
    for (int e0 = 0; e0 < 4; ++e0) {
      int k = (e0 << 8) + (e1 << 6) + klo;
      np_[k] = make_float2(rc[(e1 << 2) + e0].x * scr, rc[(e1 << 2) + e0].y * sci);
    }
}

// ---- noise linearize: transpose 1024x1024 (pairs) + roll fold ---------------
__global__ __launch_bounds__(256) void k_ntrans(const float2* __restrict__ noiseP,
                                                float* __restrict__ noiseL,
                                                const Hdr* __restrict__ h) {
  __shared__ float tr[64][65];
  __shared__ float ti[64][65];
  const int b = blockIdx.x;
  const int pair = b >> 8, tid = b & 255;
  const int R0 = (tid >> 4) << 6;
  const int C0 = (tid & 15) << 6;
  const int t = threadIdx.x;
  const int tx = t & 63, ty = t >> 6;
  const int phir = h->phi_r, phii = h->phi_i;
  const float2* src = noiseP + ((size_t)pair << 20);
  float* dstr = noiseL + ((size_t)(pair * 2) << 20);
  float* dsti = noiseL + ((size_t)(pair * 2 + 1) << 20);
  #pragma unroll
  for (int i = 0; i < 16; ++i) {
    int r = (i << 2) + ty;
    float2 v = src[(size_t)((R0 + r) << 10) + (size_t)(C0 + tx)];
    tr[r][tx] = v.x; ti[r][tx] = v.y;
  }
  __syncthreads();
  #pragma unroll
  for (int i = 0; i < 16; ++i) {
    int c = (i << 2) + ty;
    int n = ((C0 + c) << 10) + R0 + tx;
    dstr[(uint32_t)(n + phir) & (N20 - 1u)] = tr[tx][c];
    dsti[(uint32_t)(n + phii) & (N20 - 1u)] = ti[tx][c];
  }
}

// ---- forward via MFMA (register-prefetch pipelined x staging; R11 version) ---
__global__ __launch_bounds__(256, 2) void k_forward(const float* __restrict__ x,
    const float2* __restrict__ wsum, const float* __restrict__ noiseL,
    const unsigned short* __restrict__ ET, const unsigned short* __restrict__ Fc,
    const unsigned short* __restrict__ Fs, const unsigned short* __restrict__ Fns,
    float2* __restrict__ oftg) {
  __shared__ char lds[65536];
  char* X1T = lds + 32768;
  const int bc = blockIdx.x, t = threadIdx.x;
  const int c = bc & 63;
  const int l = t & 63, w = t >> 6, lr = l & 31, kg = l >> 5;
  const int rt = w >> 1, ct = w & 1;
  const float* xim = x + ((size_t)bc << 16);

  float4 pf[16];
  #pragma unroll
  for (int i = 0; i < 16; ++i) {
    int f4 = i * 256 + t;
    int r = f4 >> 6, c4 = f4 & 63;
    pf[i] = *(const float4*)(xim + (size_t)((r) << 8) + (c4 << 2));
  }

  #pragma unroll
  for (int yt = 0; yt < 4; ++yt) {
    __syncthreads();
    #pragma unroll
    for (int i = 0; i < 16; ++i) {
      int f4 = i * 256 + t;
      int r = f4 >> 6, c4 = f4 & 63;
      ushort4 b4; b4.x = f2bf(pf[i].x); b4.y = f2bf(pf[i].y);
      b4.z = f2bf(pf[i].z); b4.w = f2bf(pf[i].w);
      int byte = ((r << 9) + (c4 << 3)) ^ ((r & 7) << 4);
      *(ushort4*)(lds + byte) = b4;
    }
    __syncthreads();
    if (yt < 3) {
      #pragma unroll
      for (int i = 0; i < 16; ++i) {
        int f4 = i * 256 + t;
        int r = f4 >> 6, c4 = f4 & 63;
        pf[i] = *(const float4*)(xim + (size_t)((((yt + 1) << 6) + r) << 8) + (c4 << 2));
      }
    }
    f32x16 a1 = zero16();
    const int arow = (rt << 5) + lr;
    const int bcol = (ct << 5) + lr;
    #pragma unroll
    for (int s = 0; s < 16; ++s) {
      short8 af = *(const short8*)(lds + (((arow << 9) + (s << 5) + (kg << 4)) ^ ((arow & 7) << 4)));
      short8 bf = *(const short8*)(ET + (bcol << 8) + (s << 4) + (kg << 3));
      a1 = __builtin_amdgcn_mfma_f32_32x32x16_bf16(af, bf, a1, 0, 0, 0);
    }
    #pragma unroll
    for (int r4 = 0; r4 < 4; ++r4) {
      int y0 = (yt << 6) + (rt << 5) + (r4 << 3) + (kg << 2);
      ushort4 p4;
      p4.x = f2bf(a1[r4 * 4 + 0]); p4.y = f2bf(a1[r4 * 4 + 1]);
      p4.z = f2bf(a1[r4 * 4 + 2]); p4.w = f2bf(a1[r4 * 4 + 3]);
      int byte = ((bcol << 9) + (y0 << 1)) ^ ((bcol & 7) << 4);
      *(ushort4*)(X1T + byte) = p4;
    }
  }
  __syncthreads();

  const int re_im = w >> 1, kt = w & 1;
  const unsigned short* A1p = re_im ? Fns : Fs;
  const int b0row = (re_im ? 32 : 0) + lr;
  const int b1row = (re_im ? 0 : 32) + lr;
  const int a2row = (kt << 5) + lr;
  f32x16 a2 = zero16();
  #pragma unroll
  for (int s = 0; s < 16; ++s) {
    short8 a0f = *(const short8*)(Fc  + (a2row << 8) + (s << 4) + (kg << 3));
    short8 a1f = *(const short8*)(A1p + (a2row << 8) + (s << 4) + (kg << 3));
    short8 b0f = *(const short8*)(X1T + (((b0row << 9) + (s << 5) + (kg << 4)) ^ ((b0row & 7) << 4)));
    short8 b1f = *(const short8*)(X1T + (((b1row << 9) + (s << 5) + (kg << 4)) ^ ((b1row & 7) << 4)));
    a2 = __builtin_amdgcn_mfma_f32_32x32x16_bf16(a0f, b0f, a2, 0, 0, 0);
    a2 = __builtin_amdgcn_mfma_f32_32x32x16_bf16(a1f, b1f, a2, 0, 0, 0);
  }
  float* Osm = (float*)(lds + (re_im << 13));
  #pragma unroll
  for (int i = 0; i < 16; ++i) {
    int row = (kt << 5) + (i & 3) + ((i >> 2) << 3) + (kg << 2);
    Osm[(row << 5) + lr] = a2[i];
  }
  __syncthreads();

  const float* Ore = (const float*)lds;
  const float* Oim = (const float*)(lds + 8192);
  #pragma unroll
  for (int r = 0; r < 8; ++r) {
    int idx = (r << 8) + t;
    int kyp = idx >> 5, kx = idx & 31;
    int sel = kyp >> 5, m1 = kyp & 31;
    float2 av = make_float2(Ore[idx], Oim[idx]);
    float2 wv = wsum[((size_t)sel << 16) + (size_t)(((c << 5) | m1) << 5) + (size_t)kx];
    float2 v;
    v.x = av.x * wv.x - av.y * wv.y;
    v.y = av.x * wv.y + av.y * wv.x;
    uint32_t p = ((uint32_t)((bc << 5) | m1) << 5) | (uint32_t)kx;
    const float* nlr = noiseL + ((size_t)(sel ? 2 : 0) << 20);
    const float* nli = noiseL + ((size_t)(sel ? 3 : 1) << 20);
    v.x -= nlr[p];
    v.y -= nli[p];
    oftg[((size_t)bc << 11) + (size_t)idx] = v;
  }
}

// ---- inverse via two bf16 MFMA GEMMs per image (32KB LDS) --------------------
__global__ __launch_bounds__(256) void k_inverse(const float2* __restrict__ oftg,
    const unsigned short* __restrict__ A_E, const unsigned short* __restrict__ B2T,
    float* __restrict__ out) {
  __shared__ char smem[32768];

  const int bc = blockIdx.x, t = threadIdx.x;
  const int l = t & 63, w = t >> 6, lr = l & 31, kg = l >> 5;

  {
    const float* ob = (const float*)(oftg + ((size_t)bc << 11));
    #pragma unroll
    for (int i = 0; i < 32; ++i) {
      int idx = t + (i << 8);
      int p = idx >> 6, j = idx & 63;
      int kyp = p & 63;
      float v;
      if (p < 64) v = (j < 32) ? ob[(kyp << 6) + (j << 1)]
                               : ob[(kyp << 6) + ((j - 32) << 1) + 1];
      else        v = (j < 32) ? -ob[(kyp << 6) + (j << 1) + 1]
                               : ob[(kyp << 6) + ((j - 32) << 1)];
      int byte = ((j << 8) + (p << 1)) ^ ((j & 7) << 4);
      *(unsigned short*)(smem + byte) = f2bf(v);
    }
  }
  __syncthreads();

  f32x16 acc[2][2];
  acc[0][0] = zero16(); acc[0][1] = zero16(); acc[1][0] = zero16(); acc[1][1] = zero16();
  #pragma unroll
  for (int s = 0; s < 8; ++s) {
    short8 af[2], bf[2];
    #pragma unroll
    for (int rt = 0; rt < 2; ++rt) {
      int row = (w << 6) + (rt << 5) + lr;
      af[rt] = *(const short8*)(A_E + (row << 7) + (s << 4) + (kg << 3));
    }
    #pragma unroll
    for (int ct = 0; ct < 2; ++ct) {
      int j = (ct << 5) + lr;
      int byte = ((j << 8) + (s << 5) + (kg << 4)) ^ ((j & 7) << 4);
      bf[ct] = *(const short8*)(smem + byte);
    }
    #pragma unroll
    for (int rt = 0; rt < 2; ++rt)
      #pragma unroll
      for (int ct = 0; ct < 2; ++ct)
        acc[rt][ct] = __builtin_amdgcn_mfma_f32_32x32x16_bf16(af[rt], bf[ct], acc[rt][ct], 0, 0, 0);
  }
  __syncthreads();

  #pragma unroll
  for (int rt = 0; rt < 2; ++rt)
    #pragma unroll
    for (int ct = 0; ct < 2; ++ct)
      #pragma unroll
      for (int r = 0; r < 16; ++r) {
        int row = (w << 6) + (rt << 5) + (r & 3) + (((r >> 2) & 3) << 3) + (kg << 2);
        int col = (ct << 5) + lr;
        int byte = ((row << 7) + (col << 1)) ^ ((row & 7) << 4);
        *(unsigned short*)(smem + byte) = f2bf(acc[rt][ct][r]);
      }
  __syncthreads();

  short8 ta[2][4];
  #pragma unroll
  for (int rt = 0; rt < 2; ++rt)
    #pragma unroll
    for (int ks = 0; ks < 4; ++ks) {
      int row = (w << 6) + (rt << 5) + lr;
      int byte = ((row << 7) + (ks << 5) + (kg << 4)) ^ ((row & 7) << 4);
      ta[rt][ks] = *(const short8*)(smem + byte);
    }
  float* op = out + ((size_t)bc << 16);
  #pragma unroll
  for (int cc = 0; cc < 4; ++cc) {
    short8 b2[2][4];
    #pragma unroll
    for (int cx = 0; cx < 2; ++cx)
      #pragma unroll
      for (int ks = 0; ks < 4; ++ks) {
        int xx = (cc << 6) + (cx << 5) + lr;
        b2[cx][ks] = *(const short8*)(B2T + (xx << 6) + (ks << 4) + (kg << 3));
      }
    f32x16 a2[2][2];
    a2[0][0] = zero16(); a2[0][1] = zero16(); a2[1][0] = zero16(); a2[1][1] = zero16();
    #pragma unroll
    for (int ks = 0; ks < 4; ++ks)
      #pragma unroll
      for (int rt = 0; rt < 2; ++rt)
        #pragma unroll
        for (int cx = 0; cx < 2; ++cx)
          a2[rt][cx] = __builtin_amdgcn_mfma_f32_32x32x16_bf16(ta[rt][ks], b2[cx][ks], a2[rt][cx], 0, 0, 0);
    #pragma unroll
    for (int rt = 0; rt < 2; ++rt)
      #pragma unroll
      for (int cx = 0; cx < 2; ++cx)
        #pragma unroll
        for (int r = 0; r < 16; ++r) {
          int row = (w << 6) + (rt << 5) + (r & 3) + (((r >> 2) & 3) << 3) + (kg << 2);
          int xx = (cc << 6) + (cx << 5) + lr;
          op[(row << 8) + xx] = a2[rt][cx][r];
        }
  }
}

// ---- host -------------------------------------------------------------------
extern "C" void kernel_launch(void* const* d_in, const int* in_sizes, int n_in,
                              void* d_out, int out_size, void* d_ws, size_t ws_size,
                              hipStream_t stream) {
  (void)in_sizes; (void)n_in; (void)out_size; (void)ws_size;
  const float* x   = (const float*)d_in[0];
  const float* w1  = (const float*)d_in[1];
  const float* w2  = (const float*)d_in[2];
  const float* er  = (const float*)d_in[3];
  const float* ei  = (const float*)d_in[4];
  const float* ar  = (const float*)d_in[5];
  const float* ai  = (const float*)d_in[6];
  const float* pr  = (const float*)d_in[7];
  const float* pim = (const float*)d_in[8];
  float* out = (float*)d_out;

  char* ws = (char*)d_ws;
  Hdr*    hdr      = (Hdr*)ws;
  float*  partials = (float*)(ws + 0x1000);
  float2* wsum     = (float2*)(ws + 0x10000);
  unsigned short* A_E = (unsigned short*)(ws + 0x130000);
  unsigned short* B2T = (unsigned short*)(ws + 0x140000);
  unsigned short* ET  = (unsigned short*)(ws + 0x148000);
  unsigned short* Fc  = (unsigned short*)(ws + 0x150000);
  unsigned short* Fs  = (unsigned short*)(ws + 0x158000);
  unsigned short* Fns = (unsigned short*)(ws + 0x160000);
  float4* spT      = (float4*)(ws + 0x200000);    // ~17MB; dead after fft_s1
  float2* G        = (float2*)(ws + 0x1400000);   // 16MB; dead after fft_s2
  float2* oft      = (float2*)(ws + 0x1400000);   // aliases G
  float2* noiseP   = (float2*)(ws + 0x2400000);   // 16MB
  float*  noiseL   = (float*)(ws + 0x3400000);    // 16MB

  auto splitk = [](const uint32_t k[2], uint32_t a[2], uint32_t b[2]) {
#if JPART
    tf2x32(k[0], k[1], 0u, 0u, a[0], a[1]);
    tf2x32(k[0], k[1], 0u, 1u, b[0], b[1]);
#else
    uint32_t r0[2], r1[2];
    tf2x32(k[0], k[1], 0u, 2u, r0[0], r0[1]);
    tf2x32(k[0], k[1], 1u, 3u, r1[0], r1[1]);
    a[0] = r0[0]; a[1] = r1[0]; b[0] = r0[1]; b[1] = r1[1];
#endif
  };
  uint32_t root[2] = { 0u, 42u };
  uint32_t kA[2], kB[2], k1A[2], k2A[2], k1B[2], k2B[2];
  splitk(root, kA, kB);
  splitk(kA, k1A, k2A);
  splitk(kB, k1B, k2B);
  KeyArgs ka;
  splitk(k1A, ka.k[0], ka.k[1]);
  splitk(k2A, ka.k[2], ka.k[3]);
  splitk(k1B, ka.k[4], ka.k[5]);
  splitk(k2B, ka.k[6], ka.k[7]);

  hipLaunchKernelGGL(k_misc,      dim3(961),      dim3(256), 0, stream, hdr, er, ei, ar, ai, pr, pim,
                     w1, w2, wsum, A_E, B2T, ET, Fc, Fs, Fns);
  hipLaunchKernelGGL(k_gen,       dim3(4608),     dim3(256), 0, stream, hdr, partials, spT, ka);
  hipLaunchKernelGGL(k_sumw2_fin, dim3(1),        dim3(64),  0, stream, hdr, partials);
  hipLaunchKernelGGL(k_fft_s1,    dim3(512),      dim3(256), 0, stream, spT, G);
  hipLaunchKernelGGL(k_fft_s2,    dim3(512),      dim3(256), 0, stream, G, noiseP, hdr);
  hipLaunchKernelGGL(k_ntrans,    dim3(512),      dim3(256), 0, stream, noiseP, noiseL, hdr);
  hipLaunchKernelGGL(k_forward,   dim3(1024),     dim3(256), 0, stream, x, wsum, noiseL, ET, Fc, Fs, Fns, oft);
  hipLaunchKernelGGL(k_inverse,   dim3(1024),     dim3(256), 0, stream, oft, A_E, B2T, out);
}

// Round 14
// 260.179 us; speedup vs baseline: 1.0583x; 1.0148x over previous
//
#include <hip/hip_runtime.h>
#include <cstdint>

// ---- JAX PRNG mode switches -------------------------------------------------
#define JPART 1
#define PART_XOR 1

constexpr uint32_t N20   = 1u << 20;
constexpr uint32_t NHALF = 1u << 19;
constexpr int SPT_STRIDE = 520;   // padded row stride (float4 elems) for spT

struct Hdr {
  float e_r, e_i, amp_r, amp_i;
  int   phi_r, phi_i;
  float nhe_r, nhe_i;
  float scale_s[4];
};
struct KeyArgs { uint32_t k[8][2]; };

typedef __attribute__((ext_vector_type(8))) short short8;
typedef __attribute__((ext_vector_type(16))) float f32x16;

__device__ inline f32x16 zero16() {
  f32x16 v;
  #pragma unroll
  for (int i = 0; i < 16; ++i) v[i] = 0.f;
  return v;
}

__device__ inline unsigned short f2bf(float f) {
  uint32_t u = __float_as_uint(f);
  return (unsigned short)((u + 0x7fffu + ((u >> 16) & 1u)) >> 16);
}

// ---- Threefry2x32-20 (exact JAX cipher) ------------------------------------
__host__ __device__ inline void tf2x32(uint32_t k0, uint32_t k1, uint32_t x0, uint32_t x1,
                                       uint32_t& o0, uint32_t& o1) {
  const uint32_t ks0 = k0, ks1 = k1, ks2 = k0 ^ k1 ^ 0x1BD11BDAu;
  const uint32_t ks[3] = { ks0, ks1, ks2 };
  x0 += ks0; x1 += ks1;
  const int rot[2][4] = { {13,15,26,6}, {17,29,16,24} };
  for (int g = 0; g < 5; ++g) {
    const int* rr = rot[g & 1];
    for (int i = 0; i < 4; ++i) {
      x0 += x1;
      x1 = (x1 << rr[i]) | (x1 >> (32 - rr[i]));
      x1 ^= x0;
    }
    x0 += ks[(g + 1) % 3];
    x1 += ks[(g + 2) % 3] + (uint32_t)(g + 1);
  }
  o0 = x0; o1 = x1;
}

// ---- XLA ErfInv32 polynomial ------------------------------------------------
__device__ inline float erfinv_xla(float x) {
  float w = -log1pf(-x * x);
  float p;
  if (w < 5.0f) {
    w -= 2.5f;
    p = 2.81022636e-08f;
    p = fmaf(p, w, 3.43273939e-07f);
    p = fmaf(p, w, -3.5233877e-06f);
    p = fmaf(p, w, -4.39150654e-06f);
    p = fmaf(p, w, 0.00021858087f);
    p = fmaf(p, w, -0.00125372503f);
    p = fmaf(p, w, -0.00417768164f);
    p = fmaf(p, w, 0.246640727f);
    p = fmaf(p, w, 1.50140941f);
  } else {
    w = sqrtf(w) - 3.0f;
    p = -0.000200214257f;
    p = fmaf(p, w, 0.000100950558f);
    p = fmaf(p, w, 0.00134934322f);
    p = fmaf(p, w, -0.00367342844f);
    p = fmaf(p, w, 0.00573950773f);
    p = fmaf(p, w, -0.0076224613f);
    p = fmaf(p, w, 0.00943887047f);
    p = fmaf(p, w, 1.00167406f);
    p = fmaf(p, w, 2.83297682f);
  }
  return p * x;
}

__device__ inline float normal_from_bits(uint32_t bits) {
  uint32_t fb = (bits >> 9) | 0x3f800000u;
  float f = __uint_as_float(fb) - 1.0f;
  const float LO = -0.99999994f;
  float u = f * 2.0f + LO;
  u = fmaxf(LO, u);
  return 1.41421356f * erfinv_xla(u);
}

__device__ inline float sscale_f(uint32_t k, float nhe) {
  uint32_t kk = k ? k : 1u;
  return powf((float)kk * (1.0f / 1048576.0f), nhe);
}

__device__ inline float2 cmul(float2 a, float2 b) {
  return make_float2(a.x * b.x - a.y * b.y, a.x * b.y + a.y * b.x);
}
__device__ inline float2 wexp(float u) {
  float s, c; sincospif(2.0f * u, &s, &c); return make_float2(c, s);
}
__device__ inline float2 cadd(float2 a, float2 b){ return make_float2(a.x+b.x, a.y+b.y); }
__device__ inline float2 csub(float2 a, float2 b){ return make_float2(a.x-b.x, a.y-b.y); }
__device__ inline float2 cmuli(float2 a){ return make_float2(-a.y, a.x); }  // * (+i)

// LDS address swizzle for the FFT exchanges: <=4-way on all phases
__device__ inline int sA(int p) { return p ^ (((p >> 6) & 3) << 2) ^ ((p >> 8) & 3); }

// radix-4 DIF butterfly, sign +i, with twiddle W = omega^{n'}
__device__ inline void bfly(float2& y0, float2& y1, float2& y2, float2& y3, float2 W) {
  float2 a = cadd(y0, y2), b = csub(y0, y2);
  float2 c = cadd(y1, y3), d = cmuli(csub(y1, y3));
  float2 W2 = cmul(W, W), W3 = cmul(W2, W);
  y0 = cadd(a, c);
  y1 = cmul(cadd(b, d), W);
  y2 = cmul(csub(a, c), W2);
  y3 = cmul(csub(b, d), W3);
}

// 1024-pt FFT core (sign +), 64 threads, 16 pts/thread, 2 barriers.
__device__ inline void fft1024_core(float2* r, float2* rc, float2* buf, int w) {
  #pragma unroll
  for (int e3 = 0; e3 < 4; ++e3) {
    float2 W = wexp((float)((e3 << 6) + w) * (1.0f / 1024.0f));
    bfly(r[e3], r[e3 + 4], r[e3 + 8], r[e3 + 12], W);
  }
  {
    float2 W = wexp((float)w * (1.0f / 256.0f));
    #pragma unroll
    for (int e4 = 0; e4 < 4; ++e4)
      bfly(r[(e4 << 2) + 0], r[(e4 << 2) + 1], r[(e4 << 2) + 2], r[(e4 << 2) + 3], W);
  }
  #pragma unroll
  for (int s = 0; s < 16; ++s) buf[sA((s << 6) + w)] = r[s];
  __syncthreads();
  {
    const int e0 = w & 3;
    const int pbase = ((w >> 4) << 8) + (((w >> 2) & 3) << 6) + e0;
    float2 rb[16];
    #pragma unroll
    for (int e2 = 0; e2 < 4; ++e2)
      #pragma unroll
      for (int e1 = 0; e1 < 4; ++e1)
        rb[(e2 << 2) + e1] = buf[sA(pbase + (e2 << 4) + (e1 << 2))];
    #pragma unroll
    for (int e1 = 0; e1 < 4; ++e1) {
      float2 W = wexp((float)((e1 << 2) + e0) * (1.0f / 64.0f));
      bfly(rb[e1], rb[e1 + 4], rb[e1 + 8], rb[e1 + 12], W);
    }
    {
      float2 W = wexp((float)e0 * (1.0f / 16.0f));
      #pragma unroll
      for (int e2 = 0; e2 < 4; ++e2)
        bfly(rb[(e2 << 2) + 0], rb[(e2 << 2) + 1], rb[(e2 << 2) + 2], rb[(e2 << 2) + 3], W);
    }
    #pragma unroll
    for (int e2 = 0; e2 < 4; ++e2)
      #pragma unroll
      for (int e1 = 0; e1 < 4; ++e1)
        buf[sA(pbase + (e2 << 4) + (e1 << 2))] = rb[(e2 << 2) + e1];
  }
  __syncthreads();
  {
    const int cbase = ((w >> 4) << 8) + (((w >> 2) & 3) << 6) + ((w & 3) << 4);
    #pragma unroll
    for (int e1 = 0; e1 < 4; ++e1)
      #pragma unroll
      for (int e0 = 0; e0 < 4; ++e0)
        rc[(e1 << 2) + e0] = buf[sA(cbase + (e1 << 2) + e0)];
    #pragma unroll
    for (int e1 = 0; e1 < 4; ++e1) {
      float2 x0 = rc[(e1 << 2)], x1 = rc[(e1 << 2) + 1], x2 = rc[(e1 << 2) + 2], x3 = rc[(e1 << 2) + 3];
      float2 a = cadd(x0, x2), b = csub(x0, x2);
      float2 c = cadd(x1, x3), d = cmuli(csub(x1, x3));
      rc[(e1 << 2)]     = cadd(a, c);
      rc[(e1 << 2) + 1] = cadd(b, d);
      rc[(e1 << 2) + 2] = csub(a, c);
      rc[(e1 << 2) + 3] = csub(b, d);
    }
  }
}

// ---- scalars helper ----------------------------------------------------------
__device__ inline float med8_dev(const float* p) {
  float v[8];
  for (int i = 0; i < 8; ++i) v[i] = p[i];
  for (int i = 1; i < 8; ++i) { float key = v[i]; int j = i - 1;
    while (j >= 0 && v[j] > key) { v[j + 1] = v[j]; --j; } v[j + 1] = key; }
  return 0.5f * (v[3] + v[4]);
}

// ---- merged: scalars (blk 960) + wsum (blk 0..511) + prep (blk 512..959) ----
__global__ __launch_bounds__(256) void k_misc(Hdr* h,
    const float* er, const float* ei, const float* ar, const float* ai,
    const float* pr, const float* pim,
    const float* __restrict__ w1, const float* __restrict__ w2,
    float2* __restrict__ wsum,
    unsigned short* __restrict__ A_E, unsigned short* __restrict__ B2T,
    unsigned short* __restrict__ ET, unsigned short* __restrict__ Fc,
    unsigned short* __restrict__ Fs, unsigned short* __restrict__ Fns) {
  const int b = blockIdx.x;
  if (b == 960) {
    if (threadIdx.x) return;
    float mer = med8_dev(er), mei = med8_dev(ei);
    h->e_r = mer; h->e_i = mei;
    h->amp_r = med8_dev(ar); h->amp_i = med8_dev(ai);
    h->phi_r = (int)med8_dev(pr);
    h->phi_i = (int)med8_dev(pim);
    h->nhe_r = -0.5f * mer; h->nhe_i = -0.5f * mei;
    return;
  }
  if (b < 512) {
    int idx = b * 256 + threadIdx.x;
    int sel = idx >> 16, rem = idx & 65535;
    const float* w = sel ? w2 : w1;
    int c = rem >> 10, m1 = (rem >> 5) & 31, m2 = rem & 31;
    size_t base = (size_t)c * 131072 + (size_t)m1 * 64 + (size_t)m2 * 2;
    float sr = 0.f, si = 0.f;
    for (int oc = 0; oc < 64; ++oc) { sr += w[base + (size_t)oc * 2048]; si += w[base + (size_t)oc * 2048 + 1]; }
    wsum[idx] = make_float2(sr, si);
    return;
  }
  int t = (b - 512) * 256 + threadIdx.x;
  if (t < 32768) {
    int y = t >> 7, p = t & 127;
    int kyp = p & 63; int ky = (kyp < 32) ? kyp : kyp + 192;
    float s, c; sincospif(2.0f * (float)((ky * y) & 255) * (1.0f / 256.0f), &s, &c);
    A_E[t] = f2bf((p < 64) ? c : s);
  } else if (t < 49152) {
    int u = t - 32768;
    int x = u >> 6, j = u & 63, kx = j & 31;
    float s, c; sincospif(2.0f * (float)((kx * x) & 255) * (1.0f / 256.0f), &s, &c);
    float v = (j < 32) ? ((kx == 0) ? 1.0f : 2.0f * c)
                       : ((kx == 0) ? 0.0f : -2.0f * s);
    B2T[u] = f2bf(v * (1.0f / 65536.0f));
  } else if (t < 65536) {
    int u = t - 49152;
    int col = u >> 8, xx = u & 255; int kx = col & 31;
    float s, c; sincospif(2.0f * (float)((kx * xx) & 255) * (1.0f / 256.0f), &s, &c);
    ET[u] = f2bf((col < 32) ? c : -s);
  } else if (t < 114688) {
    int u = (t - 65536) & 16383;
    int which = (t - 65536) >> 14;
    int kyp = u >> 8, y = u & 255; int ky = (kyp < 32) ? kyp : kyp + 192;
    float s, c; sincospif(2.0f * (float)((ky * y) & 255) * (1.0f / 256.0f), &s, &c);
    if (which == 0) Fc[u] = f2bf(c);
    else if (which == 1) Fs[u] = f2bf(s);
    else Fns[u] = f2bf(-s);
  }
}

// ---- packed: sumw2+noise_spec (blk 0..4607) + forward (blk 4608..5631) -------
__global__ __launch_bounds__(256, 2) void k_gen_fwd(const Hdr* __restrict__ h,
    float* __restrict__ partials, float4* __restrict__ spT, KeyArgs ka,
    const float* __restrict__ x, const float2* __restrict__ wsum,
    const unsigned short* __restrict__ ET, const unsigned short* __restrict__ Fc,
    const unsigned short* __restrict__ Fs, const unsigned short* __restrict__ Fns,
    float2* __restrict__ oftg) {
  __shared__ char lds[65536];
  const int b = blockIdx.x;
  if (b < 512) {
    // sumw2 partial
    float* sr_ = (float*)lds;
    float* si_ = (float*)(lds + 1024);
    const float nher = h->nhe_r, nhei = h->nhe_i;
    float sr = 0.f, si = 0.f;
    for (int j = 0; j < 4; ++j) {
      uint32_t k = (uint32_t)(b * 1024 + j * 256 + threadIdx.x) + 1u;
      float fk = (float)k * (1.0f / 1048576.0f);
      float wr = powf(fk, nher), wi = powf(fk, nhei);
      if (k == NHALF) { wr *= 0.5f; wi *= 0.5f; }
      sr += wr * wr; si += wi * wi;
    }
    sr_[threadIdx.x] = sr; si_[threadIdx.x] = si; __syncthreads();
    for (int off = 128; off > 0; off >>= 1) {
      if ((int)threadIdx.x < off) { sr_[threadIdx.x] += sr_[threadIdx.x + off];
                                    si_[threadIdx.x] += si_[threadIdx.x + off]; }
      __syncthreads();
    }
    if (!threadIdx.x) { partials[b * 2] = sr_[0]; partials[b * 2 + 1] = si_[0]; }
    return;
  }
  if (b < 4608) {
    // noise spectrum gen
    const int idx = b - 512;
    const int pair = idx >> 11;
    const int bx = idx & 2047;
    const int k1 = bx >> 1, chunk = bx & 1;
    const int k2 = (chunk << 8) + (int)threadIdx.x;
    const float nher = h->nhe_r, nhei = h->nhe_i;
    float4* row = spT + (size_t)pair * (1024 * SPT_STRIDE) + (size_t)k1 * SPT_STRIDE;
    const bool extra = (k1 == 0) && (chunk == 1) && (threadIdx.x == 255);
    const int niter = extra ? 2 : 1;
    for (int it = 0; it < niter; ++it) {
      const int kk2 = (it == 0) ? k2 : 512;
      const uint32_t i = (uint32_t)k1 + ((uint32_t)kk2 << 10);
      float vals[4];
      #pragma unroll
      for (int j = 0; j < 4; ++j) {
        const uint32_t K0 = ka.k[pair * 4 + j][0], K1 = ka.k[pair * 4 + j][1];
        uint32_t o0, o1; tf2x32(K0, K1, 0u, i, o0, o1);
#if PART_XOR
        uint32_t bits = o0 ^ o1;
#else
        uint32_t bits = o1;
#endif
        float nhe = (j < 2) ? nher : nhei;
        float v = normal_from_bits(bits) * sscale_f(i, nhe);
        if (i == 0u || i == NHALF) v = (j & 1) ? 0.0f : v * 1.41421356f;
        vals[j] = v;
      }
      row[kk2] = make_float4(vals[0], vals[1], vals[2], vals[3]);
    }
    return;
  }

  // ---- forward (bc = b - 4608), R11-proven structure, no noise subtraction --
  char* X1T = lds + 32768;
  const int bc = b - 4608, t = threadIdx.x;
  const int c = bc & 63;
  const int l = t & 63, w = t >> 6, lr = l & 31, kg = l >> 5;
  const int rt = w >> 1, ct = w & 1;
  const float* xim = x + ((size_t)bc << 16);

  float4 pf[16];
  #pragma unroll
  for (int i = 0; i < 16; ++i) {
    int f4 = i * 256 + t;
    int r = f4 >> 6, c4 = f4 & 63;
    pf[i] = *(const float4*)(xim + (size_t)((r) << 8) + (c4 << 2));
  }

  #pragma unroll
  for (int yt = 0; yt < 4; ++yt) {
    __syncthreads();
    #pragma unroll
    for (int i = 0; i < 16; ++i) {
      int f4 = i * 256 + t;
      int r = f4 >> 6, c4 = f4 & 63;
      ushort4 b4; b4.x = f2bf(pf[i].x); b4.y = f2bf(pf[i].y);
      b4.z = f2bf(pf[i].z); b4.w = f2bf(pf[i].w);
      int byte = ((r << 9) + (c4 << 3)) ^ ((r & 7) << 4);
      *(ushort4*)(lds + byte) = b4;
    }
    __syncthreads();
    if (yt < 3) {
      #pragma unroll
      for (int i = 0; i < 16; ++i) {
        int f4 = i * 256 + t;
        int r = f4 >> 6, c4 = f4 & 63;
        pf[i] = *(const float4*)(xim + (size_t)((((yt + 1) << 6) + r) << 8) + (c4 << 2));
      }
    }
    f32x16 a1 = zero16();
    const int arow = (rt << 5) + lr;
    const int bcol = (ct << 5) + lr;
    #pragma unroll
    for (int s = 0; s < 16; ++s) {
      short8 af = *(const short8*)(lds + (((arow << 9) + (s << 5) + (kg << 4)) ^ ((arow & 7) << 4)));
      short8 bf = *(const short8*)(ET + (bcol << 8) + (s << 4) + (kg << 3));
      a1 = __builtin_amdgcn_mfma_f32_32x32x16_bf16(af, bf, a1, 0, 0, 0);
    }
    #pragma unroll
    for (int r4 = 0; r4 < 4; ++r4) {
      int y0 = (yt << 6) + (rt << 5) + (r4 << 3) + (kg << 2);
      ushort4 p4;
      p4.x = f2bf(a1[r4 * 4 + 0]); p4.y = f2bf(a1[r4 * 4 + 1]);
      p4.z = f2bf(a1[r4 * 4 + 2]); p4.w = f2bf(a1[r4 * 4 + 3]);
      int byte = ((bcol << 9) + (y0 << 1)) ^ ((bcol & 7) << 4);
      *(ushort4*)(X1T + byte) = p4;
    }
  }
  __syncthreads();

  const int re_im = w >> 1, kt = w & 1;
  const unsigned short* A1p = re_im ? Fns : Fs;
  const int b0row = (re_im ? 32 : 0) + lr;
  const int b1row = (re_im ? 0 : 32) + lr;
  const int a2row = (kt << 5) + lr;
  f32x16 a2 = zero16();
  #pragma unroll
  for (int s = 0; s < 16; ++s) {
    short8 a0f = *(const short8*)(Fc  + (a2row << 8) + (s << 4) + (kg << 3));
    short8 a1f = *(const short8*)(A1p + (a2row << 8) + (s << 4) + (kg << 3));
    short8 b0f = *(const short8*)(X1T + (((b0row << 9) + (s << 5) + (kg << 4)) ^ ((b0row & 7) << 4)));
    short8 b1f = *(const short8*)(X1T + (((b1row << 9) + (s << 5) + (kg << 4)) ^ ((b1row & 7) << 4)));
    a2 = __builtin_amdgcn_mfma_f32_32x32x16_bf16(a0f, b0f, a2, 0, 0, 0);
    a2 = __builtin_amdgcn_mfma_f32_32x32x16_bf16(a1f, b1f, a2, 0, 0, 0);
  }
  float* Osm = (float*)(lds + (re_im << 13));
  #pragma unroll
  for (int i = 0; i < 16; ++i) {
    int row = (kt << 5) + (i & 3) + ((i >> 2) << 3) + (kg << 2);
    Osm[(row << 5) + lr] = a2[i];
  }
  __syncthreads();

  const float* Ore = (const float*)lds;
  const float* Oim = (const float*)(lds + 8192);
  #pragma unroll
  for (int r = 0; r < 8; ++r) {
    int idx = (r << 8) + t;
    int kyp = idx >> 5, kx = idx & 31;
    int sel = kyp >> 5, m1 = kyp & 31;
    float2 av = make_float2(Ore[idx], Oim[idx]);
    float2 wv = wsum[((size_t)sel << 16) + (size_t)(((c << 5) | m1) << 5) + (size_t)kx];
    float2 v;
    v.x = av.x * wv.x - av.y * wv.y;
    v.y = av.x * wv.y + av.y * wv.x;
    oftg[((size_t)bc << 11) + (size_t)idx] = v;    // noise subtracted in k_inverse
  }
}

// ---- packed: sumw2_fin (blk 512) + irfft stage 1 (blk 0..511) ---------------
__global__ __launch_bounds__(256) void k_fin_s1(Hdr* h, const float* __restrict__ partials,
                                                const float4* __restrict__ spT,
                                                float2* __restrict__ G) {
  __shared__ float2 buf4[4][1024];
  const int b = blockIdx.x;
  if (b == 512) {
    if (threadIdx.x) return;
    float Sr = 0.f, Si = 0.f;
    for (int q = 0; q < 512; ++q) { Sr += partials[q * 2]; Si += partials[q * 2 + 1]; }
    float sig_r = 2.0f * sqrtf(Sr) * (1.0f / 1048576.0f);
    float sig_i = 2.0f * sqrtf(Si) * (1.0f / 1048576.0f);
    float s0 = h->amp_r / (sig_r * 1048576.0f);
    float s1 = (h->amp_i * h->amp_i) / (sig_i * 1048576.0f);
    h->scale_s[0] = s0; h->scale_s[1] = s1; h->scale_s[2] = s0; h->scale_s[3] = s1;
    return;
  }
  const int lin = (b & 7) * 64 + (b >> 3);
  const int pair = lin >> 8;
  const int g = threadIdx.x >> 6, w = threadIdx.x & 63;
  const int k1b = (lin & 255) << 2;
  const int k1 = k1b + g;
  const float4* sp = spT + (size_t)pair * (1024 * SPT_STRIDE);
  const int mrow = (1024 - k1) & 1023;

  float2 r[16], rc[16];
  #pragma unroll
  for (int s = 0; s < 16; ++s) {
    int k2 = (s << 6) + w;
    uint32_t k = (uint32_t)k1 + ((uint32_t)k2 << 10);
    float4 f; float2 z;
    if (k <= NHALF) {
      f = sp[(size_t)k1 * SPT_STRIDE + k2];
      z = make_float2(f.x - f.w, f.y + f.z);
    } else {
      int k2p = (k1 == 0) ? (1024 - k2) : (1023 - k2);
      f = sp[(size_t)mrow * SPT_STRIDE + k2p];
      z = make_float2(f.x + f.w, f.z - f.y);
    }
    r[s] = z;
  }
  fft1024_core(r, rc, buf4[g], w);
  const int klo = ((w & 3) << 4) + (((w >> 2) & 3) << 2) + (w >> 4);
  #pragma unroll
  for (int e1 = 0; e1 < 4; ++e1)
    #pragma unroll
    for (int e0 = 0; e0 < 4; ++e0) {
      int k = (e0 << 8) + (e1 << 6) + klo;
      float2 tw = wexp((float)(k * k1) * (1.0f / 1048576.0f));
      buf4[g][sA(k)] = cmul(rc[(e1 << 2) + e0], tw);
    }
  __syncthreads();
  const int t = threadIdx.x;
  float2* gp = G + ((size_t)pair << 20) + (size_t)k1b;
  const int k1off = t & 3;
  #pragma unroll
  for (int it = 0; it < 16; ++it) {
    int j2 = (it << 6) + (t >> 2);
    gp[((size_t)j2 << 10) + k1off] = buf4[k1off][sA(j2)];
  }
}

// ---- stage 2: per j2, FFT over k1 (coalesced row reads of G[j2][k1]) --------
__global__ __launch_bounds__(256) void k_fft_s2(const float2* __restrict__ G,
                                                float2* __restrict__ noiseP,
                                                const Hdr* __restrict__ h) {
  __shared__ float2 buf4[4][1024];
  const int b = blockIdx.x;
  const int lin = (b & 7) * 64 + (b >> 3);
  const int pair = lin >> 8;
  const int g = threadIdx.x >> 6, w = threadIdx.x & 63;
  const int j2 = ((lin & 255) << 2) + g;

  float2 r[16], rc[16];
  const float2* gp = G + ((size_t)pair << 20) + ((size_t)j2 << 10);
  #pragma unroll
  for (int s = 0; s < 16; ++s) r[s] = gp[(s << 6) + w];
  fft1024_core(r, rc, buf4[g], w);
  const float scr = h->scale_s[0], sci = h->scale_s[1];
  float2* np_ = noiseP + ((size_t)pair << 20) + ((size_t)j2 << 10);
  const int klo = ((w & 3) << 4) + (((w >> 2) & 3) << 2) + (w >> 4);
  #pragma unroll
  for (int e1 = 0; e1 < 4; ++e1)
    #pragma unroll
    for (int e0 = 0; e0 < 4; ++e0) {
      int k = (e0 << 8) + (e1 << 6) + klo;
      np_[k] = make_float2(rc[(e1 << 2) + e0].x * scr, rc[(e1 << 2) + e0].y * sci);
    }
}

// ---- noise linearize: transpose 1024x1024 (pairs) + roll fold ---------------
__global__ __launch_bounds__(256) void k_ntrans(const float2* __restrict__ noiseP,
                                                float* __restrict__ noiseL,
                                                const Hdr* __restrict__ h) {
  __shared__ float tr[64][65];
  __shared__ float ti[64][65];
  const int b = blockIdx.x;
  const int pair = b >> 8, tid = b & 255;
  const int R0 = (tid >> 4) << 6;
  const int C0 = (tid & 15) << 6;
  const int t = threadIdx.x;
  const int tx = t & 63, ty = t >> 6;
  const int phir = h->phi_r, phii = h->phi_i;
  const float2* src = noiseP + ((size_t)pair << 20);
  float* dstr = noiseL + ((size_t)(pair * 2) << 20);
  float* dsti = noiseL + ((size_t)(pair * 2 + 1) << 20);
  #pragma unroll
  for (int i = 0; i < 16; ++i) {
    int r = (i << 2) + ty;
    float2 v = src[(size_t)((R0 + r) << 10) + (size_t)(C0 + tx)];
    tr[r][tx] = v.x; ti[r][tx] = v.y;
  }
  __syncthreads();
  #pragma unroll
  for (int i = 0; i < 16; ++i) {
    int c = (i << 2) + ty;
    int n = ((C0 + c) << 10) + R0 + tx;
    dstr[(uint32_t)(n + phir) & (N20 - 1u)] = tr[tx][c];
    dsti[(uint32_t)(n + phii) & (N20 - 1u)] = ti[tx][c];
  }
}

// ---- inverse: noise subtract (in Mt build) + two bf16 MFMA GEMMs ------------
__global__ __launch_bounds__(256) void k_inverse(const float2* __restrict__ oftg,
    const float* __restrict__ noiseL,
    const unsigned short* __restrict__ A_E, const unsigned short* __restrict__ B2T,
    float* __restrict__ out) {
  __shared__ char smem[32768];

  const int bc = blockIdx.x, t = threadIdx.x;
  const int l = t & 63, w = t >> 6, lr = l & 31, kg = l >> 5;

  {
    const float* ob = (const float*)(oftg + ((size_t)bc << 11));
    const uint32_t pbase = (uint32_t)bc << 10;
    #pragma unroll
    for (int i = 0; i < 32; ++i) {
      int idx = t + (i << 8);
      int p = idx >> 6, j = idx & 63;
      int kyp = p & 63;
      int sel = kyp >> 5, m1 = kyp & 31;
      const float* nlr = noiseL + ((size_t)(sel ? 2 : 0) << 20);
      const float* nli = noiseL + ((size_t)(sel ? 3 : 1) << 20);
      int kx = (j < 32) ? j : (j - 32);
      uint32_t pn = pbase + ((uint32_t)m1 << 5) + (uint32_t)kx;
      float v;
      if (p < 64) v = (j < 32) ? (ob[(kyp << 6) + (j << 1)] - nlr[pn])
                               : (ob[(kyp << 6) + ((j - 32) << 1) + 1] - nli[pn]);
      else        v = (j < 32) ? -(ob[(kyp << 6) + (j << 1) + 1] - nli[pn])
                               : (ob[(kyp << 6) + ((j - 32) << 1)] - nlr[pn]);
      int byte = ((j << 8) + (p << 1)) ^ ((j & 7) << 4);
      *(unsigned short*)(smem + byte) = f2bf(v);
    }
  }
  __syncthreads();

  f32x16 acc[2][2];
  acc[0][0] = zero16(); acc[0][1] = zero16(); acc[1][0] = zero16(); acc[1][1] = zero16();
  #pragma unroll
  for (int s = 0; s < 8; ++s) {
    short8 af[2], bf[2];
    #pragma unroll
    for (int rt = 0; rt < 2; ++rt) {
      int row = (w << 6) + (rt << 5) + lr;
      af[rt] = *(const short8*)(A_E + (row << 7) + (s << 4) + (kg << 3));
    }
    #pragma unroll
    for (int ct = 0; ct < 2; ++ct) {
      int j = (ct << 5) + lr;
      int byte = ((j << 8) + (s << 5) + (kg << 4)) ^ ((j & 7) << 4);
      bf[ct] = *(const short8*)(smem + byte);
    }
    #pragma unroll
    for (int rt = 0; rt < 2; ++rt)
      #pragma unroll
      for (int ct = 0; ct < 2; ++ct)
        acc[rt][ct] = __builtin_amdgcn_mfma_f32_32x32x16_bf16(af[rt], bf[ct], acc[rt][ct], 0, 0, 0);
  }
  __syncthreads();

  #pragma unroll
  for (int rt = 0; rt < 2; ++rt)
    #pragma unroll
    for (int ct = 0; ct < 2; ++ct)
      #pragma unroll
      for (int r = 0; r < 16; ++r) {
        int row = (w << 6) + (rt << 5) + (r & 3) + (((r >> 2) & 3) << 3) + (kg << 2);
        int col = (ct << 5) + lr;
        int byte = ((row << 7) + (col << 1)) ^ ((row & 7) << 4);
        *(unsigned short*)(smem + byte) = f2bf(acc[rt][ct][r]);
      }
  __syncthreads();

  short8 ta[2][4];
  #pragma unroll
  for (int rt = 0; rt < 2; ++rt)
    #pragma unroll
    for (int ks = 0; ks < 4; ++ks) {
      int row = (w << 6) + (rt << 5) + lr;
      int byte = ((row << 7) + (ks << 5) + (kg << 4)) ^ ((row & 7) << 4);
      ta[rt][ks] = *(const short8*)(smem + byte);
    }
  float* op = out + ((size_t)bc << 16);
  #pragma unroll
  for (int cc = 0; cc < 4; ++cc) {
    short8 b2[2][4];
    #pragma unroll
    for (int cx = 0; cx < 2; ++cx)
      #pragma unroll
      for (int ks = 0; ks < 4; ++ks) {
        int xx = (cc << 6) + (cx << 5) + lr;
        b2[cx][ks] = *(const short8*)(B2T + (xx << 6) + (ks << 4) + (kg << 3));
      }
    f32x16 a2[2][2];
    a2[0][0] = zero16(); a2[0][1] = zero16(); a2[1][0] = zero16(); a2[1][1] = zero16();
    #pragma unroll
    for (int ks = 0; ks < 4; ++ks)
      #pragma unroll
      for (int rt = 0; rt < 2; ++rt)
        #pragma unroll
        for (int cx = 0; cx < 2; ++cx)
          a2[rt][cx] = __builtin_amdgcn_mfma_f32_32x32x16_bf16(ta[rt][ks], b2[cx][ks], a2[rt][cx], 0, 0, 0);
    #pragma unroll
    for (int rt = 0; rt < 2; ++rt)
      #pragma unroll
      for (int cx = 0; cx < 2; ++cx)
        #pragma unroll
        for (int r = 0; r < 16; ++r) {
          int row = (w << 6) + (rt << 5) + (r & 3) + (((r >> 2) & 3) << 3) + (kg << 2);
          int xx = (cc << 6) + (cx << 5) + lr;
          op[(row << 8) + xx] = a2[rt][cx][r];
        }
  }
}

// ---- host -------------------------------------------------------------------
extern "C" void kernel_launch(void* const* d_in, const int* in_sizes, int n_in,
                              void* d_out, int out_size, void* d_ws, size_t ws_size,
                              hipStream_t stream) {
  (void)in_sizes; (void)n_in; (void)out_size; (void)ws_size;
  const float* x   = (const float*)d_in[0];
  const float* w1  = (const float*)d_in[1];
  const float* w2  = (const float*)d_in[2];
  const float* er  = (const float*)d_in[3];
  const float* ei  = (const float*)d_in[4];
  const float* ar  = (const float*)d_in[5];
  const float* ai  = (const float*)d_in[6];
  const float* pr  = (const float*)d_in[7];
  const float* pim = (const float*)d_in[8];
  float* out = (float*)d_out;

  char* ws = (char*)d_ws;
  Hdr*    hdr      = (Hdr*)ws;
  float*  partials = (float*)(ws + 0x1000);
  float2* wsum     = (float2*)(ws + 0x10000);
  unsigned short* A_E = (unsigned short*)(ws + 0x130000);
  unsigned short* B2T = (unsigned short*)(ws + 0x140000);
  unsigned short* ET  = (unsigned short*)(ws + 0x148000);
  unsigned short* Fc  = (unsigned short*)(ws + 0x150000);
  unsigned short* Fs  = (unsigned short*)(ws + 0x158000);
  unsigned short* Fns = (unsigned short*)(ws + 0x160000);
  // lifetimes: spT [gen->s1], G [s1->s2], noiseP [s2->ntrans],
  //            noiseL [ntrans->inv] over dead spT, oft [gen_fwd->inv] exclusive
  float4* spT      = (float4*)(ws + 0x200000);    // ~16.3MB
  float*  noiseL   = (float*)(ws + 0x200000);     // 16MB over spT (dead after s1)
  float2* G        = (float2*)(ws + 0x1400000);   // 16MB
  float2* noiseP   = (float2*)(ws + 0x2400000);   // 16MB
  float2* oft      = (float2*)(ws + 0x3400000);   // 16MB; total ws = 68MB

  auto splitk = [](const uint32_t k[2], uint32_t a[2], uint32_t b[2]) {
#if JPART
    tf2x32(k[0], k[1], 0u, 0u, a[0], a[1]);
    tf2x32(k[0], k[1], 0u, 1u, b[0], b[1]);
#else
    uint32_t r0[2], r1[2];
    tf2x32(k[0], k[1], 0u, 2u, r0[0], r0[1]);
    tf2x32(k[0], k[1], 1u, 3u, r1[0], r1[1]);
    a[0] = r0[0]; a[1] = r1[0]; b[0] = r0[1]; b[1] = r1[1];
#endif
  };
  uint32_t root[2] = { 0u, 42u };
  uint32_t kA[2], kB[2], k1A[2], k2A[2], k1B[2], k2B[2];
  splitk(root, kA, kB);
  splitk(kA, k1A, k2A);
  splitk(kB, k1B, k2B);
  KeyArgs ka;
  splitk(k1A, ka.k[0], ka.k[1]);
  splitk(k2A, ka.k[2], ka.k[3]);
  splitk(k1B, ka.k[4], ka.k[5]);
  splitk(k2B, ka.k[6], ka.k[7]);

  hipLaunchKernelGGL(k_misc,    dim3(961),  dim3(256), 0, stream, hdr, er, ei, ar, ai, pr, pim,
                     w1, w2, wsum, A_E, B2T, ET, Fc, Fs, Fns);
  hipLaunchKernelGGL(k_gen_fwd, dim3(5632), dim3(256), 0, stream, hdr, partials, spT, ka,
                     x, wsum, ET, Fc, Fs, Fns, oft);
  hipLaunchKernelGGL(k_fin_s1,  dim3(513),  dim3(256), 0, stream, hdr, partials, spT, G);
  hipLaunchKernelGGL(k_fft_s2,  dim3(512),  dim3(256), 0, stream, G, noiseP, hdr);
  hipLaunchKernelGGL(k_ntrans,  dim3(512),  dim3(256), 0, stream, noiseP, noiseL, hdr);
  hipLaunchKernelGGL(k_inverse, dim3(1024), dim3(256), 0, stream, oft, noiseL, A_E, B2T, out);
}